// Round 25
// baseline (524.311 us; speedup 1.0000x reference)
//
#include <hip/hip_runtime.h>
#include <hip/hip_bf16.h>
#include <math.h>

// Problem constants
#define Bc 2
#define Tc 4096
#define Dc 1024
#define Hc 16
#define DKc 64
#define DVc 128
#define KDIMc 1024   // H*DK
#define VDIMc 2048   // H*DV
#define Mrows (Bc*Tc) // 8192
#define CC 64        // scan chunk size
#define NCH (Tc/CC)  // 64 chunks

typedef short short8 __attribute__((ext_vector_type(8)));
typedef float f32x4 __attribute__((ext_vector_type(4)));

__device__ __forceinline__ float siluf(float x) {
    return x / (1.f + __expf(-x));
}
__device__ __forceinline__ float dot4(float4 a, float4 b) {
    return a.x * b.x + a.y * b.y + a.z * b.z + a.w * b.w;
}
__device__ __forceinline__ unsigned short f2bf(float f) {
    unsigned int u = __float_as_uint(f);
    unsigned int r = (u + 0x7fffu + ((u >> 16) & 1u)) >> 16;
    return (unsigned short)r;
}
__device__ __forceinline__ unsigned int pk2(float a, float b) {
    return (unsigned)f2bf(a) | ((unsigned)f2bf(b) << 16);
}
__device__ __forceinline__ float bf2f(unsigned short s) {
    unsigned int u = ((unsigned int)s) << 16;
    return __uint_as_float(u);
}
// async global->LDS DMA, 16B per lane; lds base must be wave-uniform.
__device__ __forceinline__ void gload16(const unsigned short* g,
                                        unsigned short* l) {
    __builtin_amdgcn_global_load_lds(
        (const __attribute__((address_space(1))) unsigned int*)g,
        (__attribute__((address_space(3))) unsigned int*)l, 16, 0, 0);
}

// ---------------------------------------------------------------------------
// Fused prep kernel: 5 bf16 weight transposes + 2 f32 a/b transposes +
// x f32->bf16 convert, dispatched by blockIdx range (provably disjoint).
// ---------------------------------------------------------------------------
__device__ void tile_transp_bf16(const float* __restrict__ in,
                                 unsigned short* __restrict__ out, int K,
                                 int N, int blk) {
    __shared__ float t[32][33];
    const int nbx = N >> 5;
    const int n0 = (blk % nbx) << 5;
    const int k0 = (blk / nbx) << 5;
    const int c = threadIdx.x & 31, r4 = (threadIdx.x >> 5) << 2;
#pragma unroll
    for (int i = 0; i < 4; i++)
        t[r4 + i][c] = in[(size_t)(k0 + r4 + i) * N + n0 + c];
    __syncthreads();
#pragma unroll
    for (int i = 0; i < 4; i++)
        out[(size_t)(n0 + r4 + i) * K + k0 + c] = f2bf(t[c][r4 + i]);
}

__device__ void tile_transp_f32w(const float* __restrict__ in,
                                 float* __restrict__ out, int blk) {
    __shared__ float t2[64][17];
    const int k0 = blk * 64;
    const int r = threadIdx.x >> 2, c4 = (threadIdx.x & 3) << 2;
    float4 v = *(const float4*)&in[(size_t)(k0 + r) * 16 + c4];
    t2[r][c4 + 0] = v.x;
    t2[r][c4 + 1] = v.y;
    t2[r][c4 + 2] = v.z;
    t2[r][c4 + 3] = v.w;
    __syncthreads();
    const int n = threadIdx.x >> 4;
    const int kk = (threadIdx.x & 15) << 2;
    out[(size_t)n * Dc + k0 + kk + 0] = t2[kk + 0][n];
    out[(size_t)n * Dc + k0 + kk + 1] = t2[kk + 1][n];
    out[(size_t)n * Dc + k0 + kk + 2] = t2[kk + 2][n];
    out[(size_t)n * Dc + k0 + kk + 3] = t2[kk + 3][n];
}

__global__ void __launch_bounds__(256) prep_all(
    const float* __restrict__ x, const float* __restrict__ w_q,
    const float* __restrict__ w_k, const float* __restrict__ w_v,
    const float* __restrict__ w_g, const float* __restrict__ w_out,
    const float* __restrict__ w_a, const float* __restrict__ w_b,
    unsigned short* __restrict__ xb, unsigned short* __restrict__ wqT,
    unsigned short* __restrict__ wkT, unsigned short* __restrict__ wvT,
    unsigned short* __restrict__ wgT, unsigned short* __restrict__ woT,
    float* __restrict__ waT, float* __restrict__ wbT) {
    int blk = blockIdx.x;
    if (blk < 1024) { tile_transp_bf16(w_q, wqT, Dc, KDIMc, blk); return; }
    blk -= 1024;
    if (blk < 1024) { tile_transp_bf16(w_k, wkT, Dc, KDIMc, blk); return; }
    blk -= 1024;
    if (blk < 2048) { tile_transp_bf16(w_v, wvT, Dc, VDIMc, blk); return; }
    blk -= 2048;
    if (blk < 2048) { tile_transp_bf16(w_g, wgT, Dc, VDIMc, blk); return; }
    blk -= 2048;
    if (blk < 2048) { tile_transp_bf16(w_out, woT, VDIMc, Dc, blk); return; }
    blk -= 2048;
    if (blk < 16) { tile_transp_f32w(w_a, waT, blk); return; }
    blk -= 16;
    if (blk < 16) { tile_transp_f32w(w_b, wbT, blk); return; }
    blk -= 16;
    // x convert: 8192 blocks, 4 floats/thread
    int g = blk * 256 + threadIdx.x;
    float4 v = *(const float4*)&x[(size_t)g * 4];
    *(uint2*)&xb[(size_t)g * 4] = make_uint2(pk2(v.x, v.y), pk2(v.z, v.w));
}

// ---------------------------------------------------------------------------
// bf16 tile transpose: in [B][T][KDIM] -> out [B][KDIM][T]. 64x64 tiles.
// ---------------------------------------------------------------------------
__global__ void __launch_bounds__(256) transp_k16(
    const unsigned short* __restrict__ in, unsigned short* __restrict__ out) {
    __shared__ unsigned short t[64][68];  // 136B rows (8B-aligned)
    const int bx = blockIdx.x & 63;          // t-block
    const int by = (blockIdx.x >> 6) & 15;   // c-block (KDIM/64)
    const int b = blockIdx.x >> 10;
    const int t0 = bx << 6, c0 = by << 6;
    {
        const int row = threadIdx.x >> 2, c16 = (threadIdx.x & 3) << 4;
        const unsigned short* src =
            &in[((size_t)b * Tc + t0 + row) * KDIMc + c0 + c16];
#pragma unroll
        for (int i = 0; i < 4; i++)
            *(uint2*)&t[row][c16 + i * 4] = *(const uint2*)&src[i * 4];
    }
    __syncthreads();
    {
        const int cc = threadIdx.x & 63, tp = (threadIdx.x >> 6) << 4;
        unsigned short v[16];
#pragma unroll
        for (int i = 0; i < 16; i++) v[i] = t[tp + i][cc];
        unsigned short* dst =
            &out[((size_t)b * KDIMc + c0 + cc) * Tc + t0 + tp];
        *(uint4*)&dst[0] = *(uint4*)&v[0];
        *(uint4*)&dst[8] = *(uint4*)&v[8];
    }
}

// ---------------------------------------------------------------------------
// GEMM building blocks, BK=64, DOUBLE-BUFFERED single-barrier prefetch
// (T3-minimum): per K-step, issue next-tile global_load_lds into buf^1,
// then ds_read+MFMA current buf, then ONE __syncthreads() (compiler drains
// vmcnt(0)+lgkmcnt(0) before s_barrier) -- staging latency hides under MFMA.
// Race-free: buf written at step t was last read at step t-1; every wave's
// ds_reads complete (lgkmcnt) before its MFMAs, before the t-1 barrier.
// MFMA order per output element identical to the R14 2-barrier schedule.
// ---------------------------------------------------------------------------
#define GEMM_SHARED()                                                         \
    __shared__ unsigned short As0[2][128 * 32], As1[2][128 * 32];             \
    __shared__ unsigned short Bs0[2][128 * 32], Bs1[2][128 * 32];

#define GEMM_STAGE64(Ap, Bp, Kk, KT, PB)                                      \
    {                                                                         \
        const size_t kb0 = (size_t)((KT) << 6) + gcol;                        \
        const size_t kb1 = kb0 + 32;                                          \
        _Pragma("unroll") for (int r = 0; r < 2; r++) {                       \
            const int rows = r * 64 + w * 16;                                 \
            gload16(&Ap[(size_t)(m0 + rows + grow) * Kk + kb0],               \
                    &As0[PB][rows * 32]);                                     \
            gload16(&Ap[(size_t)(m0 + rows + grow) * Kk + kb1],               \
                    &As1[PB][rows * 32]);                                     \
            gload16(&Bp[(size_t)(n0 + rows + grow) * Kk + kb0],               \
                    &Bs0[PB][rows * 32]);                                     \
            gload16(&Bp[(size_t)(n0 + rows + grow) * Kk + kb1],               \
                    &Bs1[PB][rows * 32]);                                     \
        }                                                                     \
    }

#define GEMM_MFMA64(PB)                                                       \
    {                                                                         \
        short8 af[4], bfr[4];                                                 \
        _Pragma("unroll") for (int i = 0; i < 4; i++)                         \
            af[i] = *(const short8*)&As0[PB][(wr + i * 16 + fr) * 32 + fk8];  \
        _Pragma("unroll") for (int j = 0; j < 4; j++)                         \
            bfr[j] = *(const short8*)&Bs0[PB][(wc + j * 16 + fr) * 32 + fk8]; \
        _Pragma("unroll") for (int i = 0; i < 4; i++)                         \
            _Pragma("unroll") for (int j = 0; j < 4; j++)                     \
                acc[i][j] = __builtin_amdgcn_mfma_f32_16x16x32_bf16(          \
                    af[i], bfr[j], acc[i][j], 0, 0, 0);                       \
        _Pragma("unroll") for (int i = 0; i < 4; i++)                         \
            af[i] = *(const short8*)&As1[PB][(wr + i * 16 + fr) * 32 + fk8];  \
        _Pragma("unroll") for (int j = 0; j < 4; j++)                         \
            bfr[j] = *(const short8*)&Bs1[PB][(wc + j * 16 + fr) * 32 + fk8]; \
        _Pragma("unroll") for (int i = 0; i < 4; i++)                         \
            _Pragma("unroll") for (int j = 0; j < 4; j++)                     \
                acc[i][j] = __builtin_amdgcn_mfma_f32_16x16x32_bf16(          \
                    af[i], bfr[j], acc[i][j], 0, 0, 0);                       \
    }

#define GEMM_KLOOP(Ap, Bp, Kk)                                                \
    {                                                                         \
        const int nkt = (Kk) >> 6;                                            \
        GEMM_STAGE64(Ap, Bp, Kk, 0, 0);                                       \
        __syncthreads(); /* drains vmcnt(0): tile 0 ready */                  \
        int cur = 0;                                                          \
        for (int kt = 0; kt < nkt - 1; kt++) {                                \
            GEMM_STAGE64(Ap, Bp, Kk, kt + 1, cur ^ 1); /* prefetch issue */   \
            GEMM_MFMA64(cur);                          /* compute current */  \
            __syncthreads(); /* drains vmcnt(0): tile kt+1 ready */           \
            cur ^= 1;                                                         \
        }                                                                     \
        GEMM_MFMA64(cur); /* last tile */                                     \
    }

// ---------------------------------------------------------------------------
// Fused q/k/v projection GEMM: bx 0-7 -> q16, 8-15 -> k16, 16-31 -> vb f32.
// ---------------------------------------------------------------------------
__global__ void __launch_bounds__(256) gemm_qkv(
    const unsigned short* __restrict__ A, const unsigned short* __restrict__ Bt,
    unsigned short* __restrict__ q16, unsigned short* __restrict__ k16,
    float* __restrict__ vb) {
    GEMM_SHARED();
    const int tid = threadIdx.x;
    const int bx = blockIdx.x & 31, by = blockIdx.x >> 5;
    const int m0 = by << 7, n0 = bx << 7;
    const int w = tid >> 6, lane = tid & 63;
    const int wr = (w >> 1) << 6, wc = (w & 1) << 6;
    const int fr = lane & 15, fk8 = (lane >> 4) << 3;
    const int grow = lane >> 2;
    const int gcol = (lane & 3) << 3;

    f32x4 acc[4][4];
#pragma unroll
    for (int i = 0; i < 4; i++)
#pragma unroll
        for (int j = 0; j < 4; j++)
            acc[i][j] = (f32x4){0.f, 0.f, 0.f, 0.f};

    GEMM_KLOOP(A, Bt, Dc);

    const int cr = (lane >> 4) << 2;
    if (bx < 16) {
        unsigned short* Cb = (bx < 8) ? q16 : k16;
        const int coloff = (bx & 7) << 7;
#pragma unroll
        for (int i = 0; i < 4; i++)
#pragma unroll
            for (int j = 0; j < 4; j++) {
#pragma unroll
                for (int r = 0; r < 4; r++) {
                    Cb[(size_t)(m0 + wr + i * 16 + cr + r) * KDIMc + coloff +
                       wc + j * 16 + fr] = f2bf(acc[i][j][r]);
                }
            }
    } else {
        const int coloff = (bx - 16) << 7;
#pragma unroll
        for (int i = 0; i < 4; i++)
#pragma unroll
            for (int j = 0; j < 4; j++) {
#pragma unroll
                for (int r = 0; r < 4; r++) {
                    vb[(size_t)(m0 + wr + i * 16 + cr + r) * VDIMc + coloff +
                       wc + j * 16 + fr] = acc[i][j][r];
                }
            }
    }
}

// ---------------------------------------------------------------------------
// bf16 MFMA GEMM (generic): C f32 = A @ Bt. For output projection.
// ---------------------------------------------------------------------------
__global__ void __launch_bounds__(256) gemm_bf16(
    const unsigned short* __restrict__ A, const unsigned short* __restrict__ Bt,
    float* __restrict__ C, int M, int N, int K) {
    GEMM_SHARED();
    const int tid = threadIdx.x;
    const int nbx = N >> 7;
    const int bx = blockIdx.x % nbx, by = blockIdx.x / nbx;
    const int m0 = by << 7, n0 = bx << 7;
    const int w = tid >> 6, lane = tid & 63;
    const int wr = (w >> 1) << 6, wc = (w & 1) << 6;
    const int fr = lane & 15, fk8 = (lane >> 4) << 3;
    const int grow = lane >> 2;
    const int gcol = (lane & 3) << 3;

    f32x4 acc[4][4];
#pragma unroll
    for (int i = 0; i < 4; i++)
#pragma unroll
        for (int j = 0; j < 4; j++)
            acc[i][j] = (f32x4){0.f, 0.f, 0.f, 0.f};

    GEMM_KLOOP(A, Bt, K);

    const int cr = (lane >> 4) << 2;
#pragma unroll
    for (int i = 0; i < 4; i++)
#pragma unroll
        for (int j = 0; j < 4; j++) {
#pragma unroll
            for (int r = 0; r < 4; r++) {
                C[(size_t)(m0 + wr + i * 16 + cr + r) * N + n0 + wc + j * 16 +
                  fr] = acc[i][j][r];
            }
        }
}

// ---------------------------------------------------------------------------
// Gate GEMM fused with gated RMSNorm epilogue; o read as bf16.
// ---------------------------------------------------------------------------
__global__ void __launch_bounds__(256) gemm_gate_rms(
    const unsigned short* __restrict__ A, const unsigned short* __restrict__ Bt,
    const unsigned short* __restrict__ o, const float* __restrict__ rfac,
    const float* __restrict__ norm_w, unsigned short* __restrict__ out,
    int M, int N, int K) {
    GEMM_SHARED();
    const int tid = threadIdx.x;
    const int nbx = N >> 7;
    const int bx = blockIdx.x % nbx, by = blockIdx.x / nbx;
    const int m0 = by << 7, n0 = bx << 7;
    const int h = n0 >> 7;
    const int w = tid >> 6, lane = tid & 63;
    const int wr = (w >> 1) << 6, wc = (w & 1) << 6;
    const int fr = lane & 15, fk8 = (lane >> 4) << 3;
    const int grow = lane >> 2;
    const int gcol = (lane & 3) << 3;

    f32x4 acc[4][4];
#pragma unroll
    for (int i = 0; i < 4; i++)
#pragma unroll
        for (int j = 0; j < 4; j++)
            acc[i][j] = (f32x4){0.f, 0.f, 0.f, 0.f};

    GEMM_KLOOP(A, Bt, K);

    const int cr = (lane >> 4) << 2;
#pragma unroll
    for (int i = 0; i < 4; i++)
#pragma unroll
        for (int j = 0; j < 4; j++) {
            const int colh = wc + j * 16 + fr;
            const float nw = norm_w[colh];
#pragma unroll
            for (int r = 0; r < 4; r++) {
                const int row = m0 + wr + i * 16 + cr + r;
                float ov = bf2f(o[(size_t)row * VDIMc + n0 + colh]);
                float f = rfac[(size_t)row * Hc + h];
                float y = ov * f * nw * siluf(acc[i][j][r]);
                out[(size_t)row * VDIMc + n0 + colh] = f2bf(y);
            }
        }
}

// ---------------------------------------------------------------------------
// Per-(row,h) RMS factor from bf16 o: rf = rsqrt(mean(o^2)+eps).
// ---------------------------------------------------------------------------
__global__ void __launch_bounds__(256) rfac_kernel(
    const unsigned short* __restrict__ o, float* __restrict__ rf) {
    const int row = blockIdx.x * 4 + (threadIdx.x >> 6);
    const int lane = threadIdx.x & 63;
    const size_t base = (size_t)row * DVc;
    unsigned int pv = *(const unsigned int*)&o[base + lane * 2];
    float o0 = bf2f((unsigned short)(pv & 0xffff));
    float o1 = bf2f((unsigned short)(pv >> 16));
    float ss = o0 * o0 + o1 * o1;
#pragma unroll
    for (int m = 1; m < 64; m <<= 1) ss += __shfl_xor(ss, m, 64);
    if (lane == 0) rf[row] = rsqrtf(ss * (1.f / 128.f) + 1e-5f);
}

// ---------------------------------------------------------------------------
// a/b projections: transposed f32 weights, one wave per 4 rows.
// ---------------------------------------------------------------------------
__global__ void __launch_bounds__(256) ab_proj(
    const float* __restrict__ x, const float* __restrict__ w_aT,
    const float* __restrict__ w_bT, const float* __restrict__ A_log,
    const float* __restrict__ dt_bias, float* __restrict__ g_out,
    float* __restrict__ beta_out) {
    const int wv = threadIdx.x >> 6;
    const int lane = threadIdx.x & 63;
    const int h = lane >> 2, kg = lane & 3;
    const int row0 = blockIdx.x * 16 + wv * 4;
    const float* wa = w_aT + (size_t)h * Dc + kg * 256;
    const float* wb = w_bT + (size_t)h * Dc + kg * 256;
    const float* xr = x + (size_t)row0 * Dc + kg * 256;
    float pa[4] = {0.f, 0.f, 0.f, 0.f}, pb[4] = {0.f, 0.f, 0.f, 0.f};
#pragma unroll 4
    for (int k = 0; k < 256; k += 4) {
        float4 a4 = *(const float4*)&wa[k];
        float4 b4 = *(const float4*)&wb[k];
#pragma unroll
        for (int r = 0; r < 4; r++) {
            float4 x4 = *(const float4*)&xr[(size_t)r * Dc + k];
            pa[r] += dot4(x4, a4);
            pb[r] += dot4(x4, b4);
        }
    }
#pragma unroll
    for (int r = 0; r < 4; r++) {
        pa[r] += __shfl_xor(pa[r], 1, 64);
        pa[r] += __shfl_xor(pa[r], 2, 64);
        pb[r] += __shfl_xor(pb[r], 1, 64);
        pb[r] += __shfl_xor(pb[r], 2, 64);
    }
    if (kg == 0) {
        const float el = __expf(A_log[h]);
        const float db = dt_bias[h];
#pragma unroll
        for (int r = 0; r < 4; r++) {
            float arg = pa[r] + db;
            float sp = fmaxf(arg, 0.f) + log1pf(__expf(-fabsf(arg)));
            g_out[(size_t)(row0 + r) * Hc + h] = -el * sp;
            beta_out[(size_t)(row0 + r) * Hc + h] =
                2.f / (1.f + __expf(-pb[r]));
        }
    }
}

// ---------------------------------------------------------------------------
// Save 3-row halos at 64-step chunk boundaries (for in-place v conv).
// ---------------------------------------------------------------------------
template <int C>
__global__ void __launch_bounds__(256) save_halo(
    const float* __restrict__ in, float* __restrict__ halo) {
    const int g = blockIdx.x * 256 + threadIdx.x;
    const int total = Bc * (Tc / 64 - 1) * 3 * C;
    if (g >= total) return;
    const int c = g % C;
    int r = g / C;
    const int j = r % 3;
    r /= 3;
    const int chunk = r % (Tc / 64 - 1) + 1;
    const int b = r / (Tc / 64 - 1);
    halo[((size_t)(b * 64 + chunk) * 3 + j) * C + c] =
        in[((size_t)b * Tc + chunk * 64 - 3 + j) * C + c];
}

// ---------------------------------------------------------------------------
// Fused q+k depthwise causal conv1d + SiLU + l2norm, bf16->bf16.
// ---------------------------------------------------------------------------
__global__ void __launch_bounds__(256) conv_qk(
    const unsigned short* __restrict__ qin, const float* __restrict__ wq,
    unsigned short* __restrict__ qout, const unsigned short* __restrict__ kin,
    const float* __restrict__ wk, unsigned short* __restrict__ kout) {
    constexpr int C = KDIMc;
    constexpr int CB = C / 256;
    const int half = Bc * (Tc / 64) * CB;
    int bidx = blockIdx.x;
    const unsigned short* in;
    const float* w;
    unsigned short* out;
    if (bidx < half) { in = qin; w = wq; out = qout; }
    else { bidx -= half; in = kin; w = wk; out = kout; }
    const int cb = bidx % CB;
    const int tchunk = (bidx / CB) % (Tc / 64);
    const int b = bidx / (CB * (Tc / 64));
    const int c = cb * 256 + threadIdx.x;
    const int t0 = tchunk * 64;
    const float w0 = w[c * 4 + 0], w1 = w[c * 4 + 1], w2 = w[c * 4 + 2],
                w3 = w[c * 4 + 3];
    const unsigned short* src = in + (size_t)b * Tc * C + c;
    float xm3 = (t0 >= 3) ? bf2f(src[(size_t)(t0 - 3) * C]) : 0.f;
    float xm2 = (t0 >= 2) ? bf2f(src[(size_t)(t0 - 2) * C]) : 0.f;
    float xm1 = (t0 >= 1) ? bf2f(src[(size_t)(t0 - 1) * C]) : 0.f;
    unsigned short* dst = out + (size_t)b * Tc * C + c;
#pragma unroll 4
    for (int i = 0; i < 64; i++) {
        float xt = bf2f(src[(size_t)(t0 + i) * C]);
        float y = w0 * xm3 + w1 * xm2 + w2 * xm1 + w3 * xt;
        y = siluf(y);
        {
            float ss = y * y;
#pragma unroll
            for (int m = 1; m < 64; m <<= 1) ss += __shfl_xor(ss, m, 64);
            y *= rsqrtf(ss + 1e-6f);
        }
        dst[(size_t)(t0 + i) * C] = f2bf(y);
        xm3 = xm2;
        xm2 = xm1;
        xm1 = xt;
    }
}

// ---------------------------------------------------------------------------
// Depthwise causal conv1d (K=4) + SiLU, IN PLACE f32 (for v).
// ---------------------------------------------------------------------------
template <int C, bool L2N>
__global__ void __launch_bounds__(256) conv_silu_inplace(
    float* __restrict__ buf, const float* __restrict__ w,
    const float* __restrict__ halo) {
    constexpr int CB = C / 256;
    const int bidx = blockIdx.x;
    const int cb = bidx % CB;
    const int tchunk = (bidx / CB) % (Tc / 64);
    const int b = bidx / (CB * (Tc / 64));
    const int c = cb * 256 + threadIdx.x;
    const int t0 = tchunk * 64;
    const float w0 = w[c * 4 + 0], w1 = w[c * 4 + 1], w2 = w[c * 4 + 2],
                w3 = w[c * 4 + 3];
    float xm3 = 0.f, xm2 = 0.f, xm1 = 0.f;
    if (tchunk > 0) {
        const float* hp = halo + (size_t)(b * 64 + tchunk) * 3 * C + c;
        xm3 = hp[0];
        xm2 = hp[C];
        xm1 = hp[2 * C];
    }
    float* p = buf + (size_t)b * Tc * C + c;
#pragma unroll 4
    for (int i = 0; i < 64; i++) {
        float xt = p[(size_t)(t0 + i) * C];
        float y = w0 * xm3 + w1 * xm2 + w2 * xm1 + w3 * xt;
        y = siluf(y);
        if (L2N) {
            float ss = y * y;
#pragma unroll
            for (int m = 1; m < 64; m <<= 1) ss += __shfl_xor(ss, m, 64);
            y *= rsqrtf(ss + 1e-6f);
        }
        p[(size_t)(t0 + i) * C] = y;
        xm3 = xm2;
        xm2 = xm1;
        xm1 = xt;
    }
}

// ---------------------------------------------------------------------------
// TM precompute: Gram via bf16 MFMA, f32 solve (readlane broadcast).
// T,M stored bf16 [t][s].
// ---------------------------------------------------------------------------
__global__ void __launch_bounds__(256) tm_precompute(
    const unsigned short* __restrict__ kc, const unsigned short* __restrict__ qc,
    const float* __restrict__ g, const float* __restrict__ beta,
    unsigned short* __restrict__ tmT, unsigned short* __restrict__ tmM) {
    const int bid = blockIdx.x;
    const int ch = bid & (NCH - 1);
    const int bh = bid >> 6;
    const int b = bh >> 4, h = bh & 15;
    const int tid = threadIdx.x;
    const int t0 = ch * CC;

    __shared__ __align__(16) unsigned short kb16[CC][72];
    __shared__ __align__(16) unsigned short qb16[CC][72];
    __shared__ __align__(16) float AtL[CC][DKc + 4];  // A^T: AtL[s][t]
    __shared__ float cL[CC], betaL[CC];

    const size_t qk0 = (size_t)b * Tc * KDIMc + h * DKc;
    const size_t gb0 = (size_t)b * Tc * Hc + h;
    const size_t tile = (size_t)(bh * NCH + ch) * 4096;

#pragma unroll
    for (int i = 0; i < 2; i++) {
        int e = tid + i * 256;
        int r = e >> 3, c8 = (e & 7) << 3;
        *(short8*)&kb16[r][c8] =
            *(const short8*)&kc[qk0 + (size_t)(t0 + r) * KDIMc + c8];
        *(short8*)&qb16[r][c8] =
            *(const short8*)&qc[qk0 + (size_t)(t0 + r) * KDIMc + c8];
    }
    if (tid < 64) {
        float gv = g[gb0 + (size_t)(t0 + tid) * Hc];
        float cv = gv;
#pragma unroll
        for (int d = 1; d < 64; d <<= 1) {
            float nb = __shfl_up(cv, d, 64);
            if (tid >= d) cv += nb;
        }
        cL[tid] = cv;
        betaL[tid] = beta[gb0 + (size_t)(t0 + tid) * Hc];
    }
    __syncthreads();

    {
        const int w = tid >> 6, lane = tid & 63;
        const int fr = lane & 15, fk8 = (lane >> 4) << 3;
        const int rr = (lane >> 4) << 2;
        short8 ak0 = *(const short8*)&kb16[w * 16 + fr][fk8];
        short8 ak1 = *(const short8*)&kb16[w * 16 + fr][fk8 + 32];
        short8 aq0 = *(const short8*)&qb16[w * 16 + fr][fk8];
        short8 aq1 = *(const short8*)&qb16[w * 16 + fr][fk8 + 32];
#pragma unroll
        for (int j = 0; j < 4; j++) {
            short8 b0 = *(const short8*)&kb16[j * 16 + fr][fk8];
            short8 b1 = *(const short8*)&kb16[j * 16 + fr][fk8 + 32];
            f32x4 kk = (f32x4){0.f, 0.f, 0.f, 0.f};
            f32x4 qk = (f32x4){0.f, 0.f, 0.f, 0.f};
            kk = __builtin_amdgcn_mfma_f32_16x16x32_bf16(ak0, b0, kk, 0, 0, 0);
            kk = __builtin_amdgcn_mfma_f32_16x16x32_bf16(ak1, b1, kk, 0, 0, 0);
            qk = __builtin_amdgcn_mfma_f32_16x16x32_bf16(aq0, b0, qk, 0, 0, 0);
            qk = __builtin_amdgcn_mfma_f32_16x16x32_bf16(aq1, b1, qk, 0, 0, 0);
#pragma unroll
            for (int r = 0; r < 4; r++) {
                int t = w * 16 + rr + r, s = j * 16 + fr;
                float E = (s <= t) ? __expf(cL[t] - cL[s]) : 0.f;
                AtL[s][t] = (s < t) ? betaL[t] * E * kk[r] : 0.f;
                tmM[tile + (size_t)t * 64 + s] =
                    (s <= t) ? f2bf(0.125f * E * qk[r]) : (unsigned short)0;
            }
        }
    }
    __syncthreads();

    {
        const int w = tid >> 6, lane = tid & 63;
        float acc[16];
#pragma unroll
        for (int di = 0; di < 16; di++)
            acc[di] = (lane == w * 16 + di) ? 1.f : 0.f;
        // Forward substitution, fully unrolled; readlane broadcast (SALU).
#pragma unroll
        for (int s = 0; s < 64; s++) {
            float a = AtL[s][lane];
            float ds[16];
#pragma unroll
            for (int di = 0; di < 16; di++)
                ds[di] = __uint_as_float(
                    __builtin_amdgcn_readlane(__float_as_uint(acc[di]), s));
#pragma unroll
            for (int di = 0; di < 16; di++)
                acc[di] = fmaf(-a, ds[di], acc[di]);
        }
        unsigned short tb[16];
#pragma unroll
        for (int di = 0; di < 16; di++) tb[di] = f2bf(acc[di]);
        *(uint4*)&tmT[tile + (size_t)lane * 64 + w * 16] = *(uint4*)&tb[0];
        *(uint4*)&tmT[tile + (size_t)lane * 64 + w * 16 + 8] = *(uint4*)&tb[8];
    }
}

// ---------------------------------------------------------------------------
// Sequential chunk scan (R19-proven): conflict-free K^T staging, all-MFMA
// phases, register-resident S, V read f32, O stored bf16. 8-way DV split.
// ---------------------------------------------------------------------------
__global__ void __launch_bounds__(512, 2) delta_scan(
    const unsigned short* __restrict__ kc, const unsigned short* __restrict__ qc,
    const unsigned short* __restrict__ kcT,  // [B][KDIM][T]
    const float* __restrict__ vc, unsigned short* __restrict__ o16,
    const float* __restrict__ g, const float* __restrict__ beta,
    const unsigned short* __restrict__ tmT,
    const unsigned short* __restrict__ tmM) {
    const int bid = blockIdx.x;
    const int sl = bid >> 5;   // 0..7
    const int bh = bid & 31;   // 0..31 -> XCD = bh%8
    const int b = bh >> 4, h = bh & 15;
    const int tid = threadIdx.x;

    __shared__ __align__(16) float VL[CC][20];
    __shared__ float gamL[CC], egL[CC], betaL[CC];
    __shared__ __align__(16) unsigned short kb16[CC][72];  // K rows
    __shared__ __align__(16) unsigned short kh16[CC][72];  // K^T: [dk][t]
    __shared__ __align__(16) unsigned short qb16[CC][72];
    __shared__ __align__(16) unsigned short Tb16[CC][72];
    __shared__ __align__(16) unsigned short Mb16[CC][72];
    __shared__ __align__(16) unsigned short STb16[16][72];  // S^T bf16 copy
    __shared__ __align__(16) unsigned short DTb16[16][72];  // RHS^T bf16
    __shared__ __align__(16) unsigned short D2b16[16][72];  // delta^T bf16
    __shared__ __align__(16) unsigned short egd16[16][72];  // (eg*delta)^T

    const size_t qk0 = (size_t)b * Tc * KDIMc + h * DKc;
    const size_t kT0 = ((size_t)b * KDIMc + h * DKc) * Tc;
    const size_t v0 = (size_t)b * Tc * VDIMc + h * DVc + sl * 16;
    const size_t gb0 = (size_t)b * Tc * Hc + h;
    const size_t tb0 = (size_t)(bh * NCH) * 4096;

    for (int i = tid; i < 16 * 72; i += 512) ((unsigned short*)STb16)[i] = 0;

    const int r8 = tid >> 3, c8 = (tid & 7) << 3;  // bf16 staging coords
    const int wid = tid >> 6, lane = tid & 63;
    const int fr = lane & 15;
    const int fk8 = (lane >> 4) << 3;
    const int rr = (lane >> 4) << 2;

    f32x4 accS = (f32x4){0.f, 0.f, 0.f, 0.f};  // waves 0-3: S[w*16+rr+r][fr]

    short8 kv, kvT, qv, tv, mv;
    float4 vv0;
    float gvr = 0.f, bvr = 0.f;

#define LOADREGS(CH)                                                          \
    {                                                                         \
        const size_t tK = qk0 + (size_t)(CH) * CC * KDIMc;                    \
        const size_t tile_ = tb0 + (size_t)(CH) * 4096;                       \
        kv = *(const short8*)&kc[tK + (size_t)r8 * KDIMc + c8];               \
        kvT = *(const short8*)&kcT[kT0 + (size_t)r8 * Tc + (CH) * CC + c8];   \
        qv = *(const short8*)&qc[tK + (size_t)r8 * KDIMc + c8];               \
        tv = *(const short8*)&tmT[tile_ + (size_t)tid * 8];                   \
        mv = *(const short8*)&tmM[tile_ + (size_t)tid * 8];                   \
        if (tid < 256)                                                        \
            vv0 = *(const float4*)&vc[v0 +                                    \
                                      (size_t)((CH) * CC + (tid >> 2)) *     \
                                          VDIMc +                             \
                                      ((tid & 3) << 2)];                      \
        if (tid < 64) {                                                       \
            gvr = g[gb0 + (size_t)((CH) * CC + tid) * Hc];                    \
            bvr = beta[gb0 + (size_t)((CH) * CC + tid) * Hc];                 \
        }                                                                     \
    }

    LOADREGS(0);

#pragma unroll 1
    for (int ch = 0; ch < NCH; ch++) {
        __syncthreads();  // B0: prev chunk fully done (STb16 visible)

        // ---- stage regs -> LDS (pure short8 copies; no conversions)
        {
            *(short8*)&kb16[r8][c8] = kv;
            *(short8*)&kh16[r8][c8] = kvT;
            *(short8*)&qb16[r8][c8] = qv;
            *(short8*)&Tb16[r8][c8] = tv;
            *(short8*)&Mb16[r8][c8] = mv;
            if (tid < 256) *(float4*)&VL[tid >> 2][(tid & 3) << 2] = vv0;
            if (tid < 64) {
                float cv = gvr;
#pragma unroll
                for (int d = 1; d < 64; d <<= 1) {
                    float nb = __shfl_up(cv, d, 64);
                    if (tid >= d) cv += nb;
                }
                gamL[tid] = __expf(cv);
                float cend = __shfl(cv, 63, 64);
                egL[tid] = __expf(cend - cv);
                betaL[tid] = bvr;
            }
        }
        if (ch + 1 < NCH) LOADREGS(ch + 1);
        __syncthreads();  // B1: stage visible

        // ---- phase 1: KS (waves 0-3) and QS (waves 4-7) via MFMA
        f32x4 acc1 = (f32x4){0.f, 0.f, 0.f, 0.f};
        {
            short8 bs0 = *(const short8*)&STb16[fr][fk8];
            short8 bs1 = *(const short8*)&STb16[fr][fk8 + 32];
            if (wid < 4) {
                const int m0 = wid << 4;
                short8 a0 = *(const short8*)&kb16[m0 + fr][fk8];
                short8 a1 = *(const short8*)&kb16[m0 + fr][fk8 + 32];
                acc1 = __builtin_amdgcn_mfma_f32_16x16x32_bf16(a0, bs0, acc1, 0, 0, 0);
                acc1 = __builtin_amdgcn_mfma_f32_16x16x32_bf16(a1, bs1, acc1, 0, 0, 0);
#pragma unroll
                for (int r = 0; r < 4; r++) {
                    int t = m0 + rr + r;
                    float rhs = betaL[t] * (VL[t][fr] - gamL[t] * acc1[r]);
                    DTb16[fr][t] = f2bf(rhs);
                }
            } else {
                const int m0 = (wid - 4) << 4;
                short8 a0 = *(const short8*)&qb16[m0 + fr][fk8];
                short8 a1 = *(const short8*)&qb16[m0 + fr][fk8 + 32];
                acc1 = __builtin_amdgcn_mfma_f32_16x16x32_bf16(a0, bs0, acc1, 0, 0, 0);
                acc1 = __builtin_amdgcn_mfma_f32_16x16x32_bf16(a1, bs1, acc1, 0, 0, 0);
#pragma unroll
                for (int r = 0; r < 4; r++) {
                    int t = m0 + rr + r;
                    acc1[r] *= 0.125f * gamL[t];
                }
            }
        }
        __syncthreads();  // B2: RHS ready

        // ---- phase 2: delta = T * RHS (waves 0-3); write delta and eg*delta
        if (wid < 4) {
            const int m0 = wid << 4;
            short8 a0 = *(const short8*)&Tb16[m0 + fr][fk8];
            short8 a1 = *(const short8*)&Tb16[m0 + fr][fk8 + 32];
            short8 b0 = *(const short8*)&DTb16[fr][fk8];
            short8 b1 = *(const short8*)&DTb16[fr][fk8 + 32];
            f32x4 d = (f32x4){0.f, 0.f, 0.f, 0.f};
            d = __builtin_amdgcn_mfma_f32_16x16x32_bf16(a0, b0, d, 0, 0, 0);
            d = __builtin_amdgcn_mfma_f32_16x16x32_bf16(a1, b1, d, 0, 0, 0);
#pragma unroll
            for (int r = 0; r < 4; r++) {
                int t = m0 + rr + r;
                D2b16[fr][t] = f2bf(d[r]);
                egd16[fr][t] = f2bf(egL[t] * d[r]);
            }
        }
        __syncthreads();  // B3: delta ready

        // ---- phase 3 (waves 4-7): O = M*delta + scaledQS, store bf16.
        //      phase 4 (waves 0-3): S = ge*S + K^T(eg*delta) via MFMA.
        if (wid >= 4) {
            const int m0 = (wid - 4) << 4;
            short8 a0 = *(const short8*)&Mb16[m0 + fr][fk8];
            short8 a1 = *(const short8*)&Mb16[m0 + fr][fk8 + 32];
            short8 b0 = *(const short8*)&D2b16[fr][fk8];
            short8 b1 = *(const short8*)&D2b16[fr][fk8 + 32];
            f32x4 o = acc1;  // 0.125*gam*QS
            o = __builtin_amdgcn_mfma_f32_16x16x32_bf16(a0, b0, o, 0, 0, 0);
            o = __builtin_amdgcn_mfma_f32_16x16x32_bf16(a1, b1, o, 0, 0, 0);
#pragma unroll
            for (int r = 0; r < 4; r++)
                o16[v0 + (size_t)(ch * CC + m0 + rr + r) * VDIMc + fr] =
                    f2bf(o[r]);
        } else {
            const int m0 = wid << 4;
            const float ge = gamL[63];
            short8 a0 = *(const short8*)&kh16[m0 + fr][fk8];
            short8 a1 = *(const short8*)&kh16[m0 + fr][fk8 + 32];
            short8 b0 = *(const short8*)&egd16[fr][fk8];
            short8 b1 = *(const short8*)&egd16[fr][fk8 + 32];
#pragma unroll
            for (int r = 0; r < 4; r++) accS[r] *= ge;
            accS = __builtin_amdgcn_mfma_f32_16x16x32_bf16(a0, b0, accS, 0, 0, 0);
            accS = __builtin_amdgcn_mfma_f32_16x16x32_bf16(a1, b1, accS, 0, 0, 0);
#pragma unroll
            for (int r = 0; r < 4; r++)
                STb16[fr][m0 + rr + r] = f2bf(accS[r]);
        }
    }
#undef LOADREGS
}

// ---------------------------------------------------------------------------
// Workspace (floats), 236 MB (R18/R19-proven layout):
//   qb 8.39M (q16raw -> kcT16) | kb 8.39M (k16raw -> o16) | vb 16.78M f32 |
//   tm-region 16.78M (tmT16|tmM16|qc16|kc16 shorts; halo aliases start) |
//   gbuf | bbuf | xtra.  obb aliases tm start (after scan); rfac = gbuf.
// ---------------------------------------------------------------------------
extern "C" void kernel_launch(void* const* d_in, const int* in_sizes, int n_in,
                              void* d_out, int out_size, void* d_ws,
                              size_t ws_size, hipStream_t stream) {
    const float* x = (const float*)d_in[0];
    const float* w_q = (const float*)d_in[1];
    const float* w_k = (const float*)d_in[2];
    const float* w_v = (const float*)d_in[3];
    const float* w_a = (const float*)d_in[4];
    const float* w_b = (const float*)d_in[5];
    const float* w_g = (const float*)d_in[6];
    const float* w_out = (const float*)d_in[7];
    const float* A_log = (const float*)d_in[8];
    const float* dt_bias = (const float*)d_in[9];
    const float* conv_q = (const float*)d_in[10];
    const float* conv_k = (const float*)d_in[11];
    const float* conv_v = (const float*)d_in[12];
    const float* norm_w = (const float*)d_in[13];

    float* ws = (float*)d_ws;
    const size_t M = Mrows;
    float* qb = ws;
    float* kb = qb + M * KDIMc;
    float* vb = kb + M * KDIMc;
    float* tm = vb + M * VDIMc;          // 16.78M floats region
    float* gbuf = tm + M * VDIMc;
    float* bbuf = gbuf + M * Hc;
    float* xtra = bbuf + M * Hc;

    unsigned short* q16raw = (unsigned short*)qb;
    unsigned short* k16raw = (unsigned short*)kb;
    unsigned short* kcT16 = (unsigned short*)qb;  // alias: after conv_q
    unsigned short* o16 = (unsigned short*)kb;    // alias: after conv_k
    unsigned short* tmS = (unsigned short*)tm;
    unsigned short* tmT16 = tmS;
    unsigned short* tmM16 = tmS + (size_t)8388608;
    unsigned short* qc16 = tmS + (size_t)16777216;
    unsigned short* kc16 = tmS + (size_t)25165824;
    float* halo = tm;                     // dead before tm_precompute
    unsigned short* obb = tmS;            // after scan, tmT/tmM dead
    float* rfac = gbuf;                   // g dead after scan

    unsigned short* xb = (unsigned short*)xtra;
    unsigned short* wqT = xb + M * KDIMc;
    unsigned short* wkT = wqT + (size_t)KDIMc * Dc;
    unsigned short* wvT = wkT + (size_t)KDIMc * Dc;  // wqT|wkT|wvT contiguous
    unsigned short* wgT = wvT + (size_t)VDIMc * Dc;
    unsigned short* woT = wgT + (size_t)VDIMc * Dc;
    float* waT = (float*)(woT + (size_t)Dc * VDIMc);
    float* wbT = waT + (size_t)16 * Dc;

    // 0) fused prep: weight transposes + a/b transposes + x convert
    prep_all<<<dim3(1024 + 1024 + 2048 + 2048 + 2048 + 16 + 16 + 8192), 256,
               0, stream>>>(x, w_q, w_k, w_v, w_g, w_out, w_a, w_b, xb, wqT,
                            wkT, wvT, wgT, woT, waT, wbT);

    // 1) fused q/k/v projection (one GEMM, BK=64; q/k out bf16, v f32)
    gemm_qkv<<<dim3((M / 128) * 32), 256, 0, stream>>>(xb, wqT, q16raw, k16raw,
                                                       vb);

    // 2) a/b projections -> g, beta
    ab_proj<<<dim3(M / 16), 256, 0, stream>>>(x, waT, wbT, A_log, dt_bias,
                                              gbuf, bbuf);

    // 3) conv + silu: fused q+k bf16->bf16 (+l2norm); v in-place f32
    conv_qk<<<dim3(2 * Bc * (Tc / 64) * (KDIMc / 256)), 256, 0, stream>>>(
        q16raw, conv_q, qc16, k16raw, conv_k, kc16);
    // kcT16 = kc16 transposed to [B][KDIM][T] (aliases qb; conv_q done)
    transp_k16<<<dim3(Bc * 16 * 64), 256, 0, stream>>>(kc16, kcT16);
    {
        const int nv = Bc * (Tc / 64 - 1) * 3 * VDIMc;
        save_halo<VDIMc><<<dim3((nv + 255) / 256), 256, 0, stream>>>(vb, halo);
        conv_silu_inplace<VDIMc, false>
            <<<dim3(Bc * (Tc / 64) * (VDIMc / 256)), 256, 0, stream>>>(
                vb, conv_v, halo);
    }

    // 4a) parallel precompute of T=(I+A)^{-1} and M (bf16 out)
    tm_precompute<<<dim3(Bc * Hc * NCH), 256, 0, stream>>>(
        kc16, qc16, gbuf, bbuf, tmT16, tmM16);
    // 4b) sequential scan (8-way DV split, R19-proven)
    delta_scan<<<dim3(Bc * Hc * 8), 512, 0, stream>>>(
        kc16, qc16, kcT16, vb, o16, gbuf, bbuf, tmT16, tmM16);

    // 5) rms factors from bf16 o, then gate GEMM fused with rms epilogue
    rfac_kernel<<<dim3(M * Hc / 4), 256, 0, stream>>>(o16, rfac);
    gemm_gate_rms<<<dim3((M / 128) * (VDIMc / 128)), 256, 0, stream>>>(
        xb, wgT, o16, rfac, norm_w, obb, M, VDIMc, Dc);

    // 6) output projection (bf16 MFMA, BK=64) -> d_out
    gemm_bf16<<<dim3((M / 128) * (Dc / 128)), 256, 0, stream>>>(
        obb, woT, (float*)d_out, M, Dc, VDIMc);
}

// Round 26
// 496.335 us; speedup vs baseline: 1.0564x; 1.0564x over previous
//
#include <hip/hip_runtime.h>
#include <hip/hip_bf16.h>
#include <math.h>

// Problem constants
#define Bc 2
#define Tc 4096
#define Dc 1024
#define Hc 16
#define DKc 64
#define DVc 128
#define KDIMc 1024   // H*DK
#define VDIMc 2048   // H*DV
#define Mrows (Bc*Tc) // 8192
#define CC 64        // scan chunk size
#define NCH (Tc/CC)  // 64 chunks

typedef short short8 __attribute__((ext_vector_type(8)));
typedef float f32x4 __attribute__((ext_vector_type(4)));

__device__ __forceinline__ float siluf(float x) {
    return x / (1.f + __expf(-x));
}
__device__ __forceinline__ float dot4(float4 a, float4 b) {
    return a.x * b.x + a.y * b.y + a.z * b.z + a.w * b.w;
}
__device__ __forceinline__ unsigned short f2bf(float f) {
    unsigned int u = __float_as_uint(f);
    unsigned int r = (u + 0x7fffu + ((u >> 16) & 1u)) >> 16;
    return (unsigned short)r;
}
__device__ __forceinline__ unsigned int pk2(float a, float b) {
    return (unsigned)f2bf(a) | ((unsigned)f2bf(b) << 16);
}
__device__ __forceinline__ float bf2f(unsigned short s) {
    unsigned int u = ((unsigned int)s) << 16;
    return __uint_as_float(u);
}
// async global->LDS DMA, 16B per lane; lds base must be wave-uniform.
__device__ __forceinline__ void gload16(const unsigned short* g,
                                        unsigned short* l) {
    __builtin_amdgcn_global_load_lds(
        (const __attribute__((address_space(1))) unsigned int*)g,
        (__attribute__((address_space(3))) unsigned int*)l, 16, 0, 0);
}

// ---------------------------------------------------------------------------
// Fused prep kernel: 5 bf16 weight transposes + 2 f32 a/b transposes +
// x f32->bf16 convert, dispatched by blockIdx range (provably disjoint).
// ---------------------------------------------------------------------------
__device__ void tile_transp_bf16(const float* __restrict__ in,
                                 unsigned short* __restrict__ out, int K,
                                 int N, int blk) {
    __shared__ float t[32][33];
    const int nbx = N >> 5;
    const int n0 = (blk % nbx) << 5;
    const int k0 = (blk / nbx) << 5;
    const int c = threadIdx.x & 31, r4 = (threadIdx.x >> 5) << 2;
#pragma unroll
    for (int i = 0; i < 4; i++)
        t[r4 + i][c] = in[(size_t)(k0 + r4 + i) * N + n0 + c];
    __syncthreads();
#pragma unroll
    for (int i = 0; i < 4; i++)
        out[(size_t)(n0 + r4 + i) * K + k0 + c] = f2bf(t[c][r4 + i]);
}

__device__ void tile_transp_f32w(const float* __restrict__ in,
                                 float* __restrict__ out, int blk) {
    __shared__ float t2[64][17];
    const int k0 = blk * 64;
    const int r = threadIdx.x >> 2, c4 = (threadIdx.x & 3) << 2;
    float4 v = *(const float4*)&in[(size_t)(k0 + r) * 16 + c4];
    t2[r][c4 + 0] = v.x;
    t2[r][c4 + 1] = v.y;
    t2[r][c4 + 2] = v.z;
    t2[r][c4 + 3] = v.w;
    __syncthreads();
    const int n = threadIdx.x >> 4;
    const int kk = (threadIdx.x & 15) << 2;
    out[(size_t)n * Dc + k0 + kk + 0] = t2[kk + 0][n];
    out[(size_t)n * Dc + k0 + kk + 1] = t2[kk + 1][n];
    out[(size_t)n * Dc + k0 + kk + 2] = t2[kk + 2][n];
    out[(size_t)n * Dc + k0 + kk + 3] = t2[kk + 3][n];
}

__global__ void __launch_bounds__(256) prep_all(
    const float* __restrict__ x, const float* __restrict__ w_q,
    const float* __restrict__ w_k, const float* __restrict__ w_v,
    const float* __restrict__ w_g, const float* __restrict__ w_out,
    const float* __restrict__ w_a, const float* __restrict__ w_b,
    unsigned short* __restrict__ xb, unsigned short* __restrict__ wqT,
    unsigned short* __restrict__ wkT, unsigned short* __restrict__ wvT,
    unsigned short* __restrict__ wgT, unsigned short* __restrict__ woT,
    float* __restrict__ waT, float* __restrict__ wbT) {
    int blk = blockIdx.x;
    if (blk < 1024) { tile_transp_bf16(w_q, wqT, Dc, KDIMc, blk); return; }
    blk -= 1024;
    if (blk < 1024) { tile_transp_bf16(w_k, wkT, Dc, KDIMc, blk); return; }
    blk -= 1024;
    if (blk < 2048) { tile_transp_bf16(w_v, wvT, Dc, VDIMc, blk); return; }
    blk -= 2048;
    if (blk < 2048) { tile_transp_bf16(w_g, wgT, Dc, VDIMc, blk); return; }
    blk -= 2048;
    if (blk < 2048) { tile_transp_bf16(w_out, woT, VDIMc, Dc, blk); return; }
    blk -= 2048;
    if (blk < 16) { tile_transp_f32w(w_a, waT, blk); return; }
    blk -= 16;
    if (blk < 16) { tile_transp_f32w(w_b, wbT, blk); return; }
    blk -= 16;
    // x convert: 8192 blocks, 4 floats/thread
    int g = blk * 256 + threadIdx.x;
    float4 v = *(const float4*)&x[(size_t)g * 4];
    *(uint2*)&xb[(size_t)g * 4] = make_uint2(pk2(v.x, v.y), pk2(v.z, v.w));
}

// ---------------------------------------------------------------------------
// bf16 tile transpose: in [B][T][KDIM] -> out [B][KDIM][T]. 64x64 tiles.
// ---------------------------------------------------------------------------
__global__ void __launch_bounds__(256) transp_k16(
    const unsigned short* __restrict__ in, unsigned short* __restrict__ out) {
    __shared__ unsigned short t[64][68];  // 136B rows (8B-aligned)
    const int bx = blockIdx.x & 63;          // t-block
    const int by = (blockIdx.x >> 6) & 15;   // c-block (KDIM/64)
    const int b = blockIdx.x >> 10;
    const int t0 = bx << 6, c0 = by << 6;
    {
        const int row = threadIdx.x >> 2, c16 = (threadIdx.x & 3) << 4;
        const unsigned short* src =
            &in[((size_t)b * Tc + t0 + row) * KDIMc + c0 + c16];
#pragma unroll
        for (int i = 0; i < 4; i++)
            *(uint2*)&t[row][c16 + i * 4] = *(const uint2*)&src[i * 4];
    }
    __syncthreads();
    {
        const int cc = threadIdx.x & 63, tp = (threadIdx.x >> 6) << 4;
        unsigned short v[16];
#pragma unroll
        for (int i = 0; i < 16; i++) v[i] = t[tp + i][cc];
        unsigned short* dst =
            &out[((size_t)b * KDIMc + c0 + cc) * Tc + t0 + tp];
        *(uint4*)&dst[0] = *(uint4*)&v[0];
        *(uint4*)&dst[8] = *(uint4*)&v[8];
    }
}

// ---------------------------------------------------------------------------
// GEMM building blocks, BK=64, single-buffered (R14-proven schedule).
// ---------------------------------------------------------------------------
#define GEMM_SHARED()                                                         \
    __shared__ unsigned short As0[128 * 32], As1[128 * 32];                   \
    __shared__ unsigned short Bs0[128 * 32], Bs1[128 * 32];

#define GEMM_STAGE64(Ap, Bp, Kk)                                              \
    {                                                                         \
        const size_t kb0 = (size_t)(kt << 6) + gcol;                          \
        const size_t kb1 = kb0 + 32;                                          \
        _Pragma("unroll") for (int r = 0; r < 2; r++) {                       \
            const int rows = r * 64 + w * 16;                                 \
            gload16(&Ap[(size_t)(m0 + rows + grow) * Kk + kb0],               \
                    &As0[rows * 32]);                                         \
            gload16(&Ap[(size_t)(m0 + rows + grow) * Kk + kb1],               \
                    &As1[rows * 32]);                                         \
            gload16(&Bp[(size_t)(n0 + rows + grow) * Kk + kb0],               \
                    &Bs0[rows * 32]);                                         \
            gload16(&Bp[(size_t)(n0 + rows + grow) * Kk + kb1],               \
                    &Bs1[rows * 32]);                                         \
        }                                                                     \
    }

#define GEMM_MFMA64()                                                         \
    {                                                                         \
        short8 af[4], bfr[4];                                                 \
        _Pragma("unroll") for (int i = 0; i < 4; i++)                         \
            af[i] = *(const short8*)&As0[(wr + i * 16 + fr) * 32 + fk8];      \
        _Pragma("unroll") for (int j = 0; j < 4; j++)                         \
            bfr[j] = *(const short8*)&Bs0[(wc + j * 16 + fr) * 32 + fk8];     \
        _Pragma("unroll") for (int i = 0; i < 4; i++)                         \
            _Pragma("unroll") for (int j = 0; j < 4; j++)                     \
                acc[i][j] = __builtin_amdgcn_mfma_f32_16x16x32_bf16(          \
                    af[i], bfr[j], acc[i][j], 0, 0, 0);                       \
        _Pragma("unroll") for (int i = 0; i < 4; i++)                         \
            af[i] = *(const short8*)&As1[(wr + i * 16 + fr) * 32 + fk8];      \
        _Pragma("unroll") for (int j = 0; j < 4; j++)                         \
            bfr[j] = *(const short8*)&Bs1[(wc + j * 16 + fr) * 32 + fk8];     \
        _Pragma("unroll") for (int i = 0; i < 4; i++)                         \
            _Pragma("unroll") for (int j = 0; j < 4; j++)                     \
                acc[i][j] = __builtin_amdgcn_mfma_f32_16x16x32_bf16(          \
                    af[i], bfr[j], acc[i][j], 0, 0, 0);                       \
    }

#define GEMM_KLOOP(Ap, Bp, Kk)                                                \
    {                                                                         \
        const int nkt = (Kk) >> 6;                                            \
        for (int kt = 0; kt < nkt; kt++) {                                    \
            __syncthreads();                                                  \
            GEMM_STAGE64(Ap, Bp, Kk);                                         \
            __syncthreads();                                                  \
            GEMM_MFMA64();                                                    \
        }                                                                     \
    }

// ---------------------------------------------------------------------------
// Fused q/k/v projection GEMM: bx 0-7 -> q16, 8-15 -> k16, 16-31 -> vb f32.
// ---------------------------------------------------------------------------
__global__ void __launch_bounds__(256) gemm_qkv(
    const unsigned short* __restrict__ A, const unsigned short* __restrict__ Bt,
    unsigned short* __restrict__ q16, unsigned short* __restrict__ k16,
    float* __restrict__ vb) {
    GEMM_SHARED();
    const int tid = threadIdx.x;
    const int bx = blockIdx.x & 31, by = blockIdx.x >> 5;
    const int m0 = by << 7, n0 = bx << 7;
    const int w = tid >> 6, lane = tid & 63;
    const int wr = (w >> 1) << 6, wc = (w & 1) << 6;
    const int fr = lane & 15, fk8 = (lane >> 4) << 3;
    const int grow = lane >> 2;
    const int gcol = (lane & 3) << 3;

    f32x4 acc[4][4];
#pragma unroll
    for (int i = 0; i < 4; i++)
#pragma unroll
        for (int j = 0; j < 4; j++)
            acc[i][j] = (f32x4){0.f, 0.f, 0.f, 0.f};

    GEMM_KLOOP(A, Bt, Dc);

    const int cr = (lane >> 4) << 2;
    if (bx < 16) {
        unsigned short* Cb = (bx < 8) ? q16 : k16;
        const int coloff = (bx & 7) << 7;
#pragma unroll
        for (int i = 0; i < 4; i++)
#pragma unroll
            for (int j = 0; j < 4; j++) {
#pragma unroll
                for (int r = 0; r < 4; r++) {
                    Cb[(size_t)(m0 + wr + i * 16 + cr + r) * KDIMc + coloff +
                       wc + j * 16 + fr] = f2bf(acc[i][j][r]);
                }
            }
    } else {
        const int coloff = (bx - 16) << 7;
#pragma unroll
        for (int i = 0; i < 4; i++)
#pragma unroll
            for (int j = 0; j < 4; j++) {
#pragma unroll
                for (int r = 0; r < 4; r++) {
                    vb[(size_t)(m0 + wr + i * 16 + cr + r) * VDIMc + coloff +
                       wc + j * 16 + fr] = acc[i][j][r];
                }
            }
    }
}

// ---------------------------------------------------------------------------
// bf16 MFMA GEMM (generic): C f32 = A @ Bt. For output projection.
// ---------------------------------------------------------------------------
__global__ void __launch_bounds__(256) gemm_bf16(
    const unsigned short* __restrict__ A, const unsigned short* __restrict__ Bt,
    float* __restrict__ C, int M, int N, int K) {
    GEMM_SHARED();
    const int tid = threadIdx.x;
    const int nbx = N >> 7;
    const int bx = blockIdx.x % nbx, by = blockIdx.x / nbx;
    const int m0 = by << 7, n0 = bx << 7;
    const int w = tid >> 6, lane = tid & 63;
    const int wr = (w >> 1) << 6, wc = (w & 1) << 6;
    const int fr = lane & 15, fk8 = (lane >> 4) << 3;
    const int grow = lane >> 2;
    const int gcol = (lane & 3) << 3;

    f32x4 acc[4][4];
#pragma unroll
    for (int i = 0; i < 4; i++)
#pragma unroll
        for (int j = 0; j < 4; j++)
            acc[i][j] = (f32x4){0.f, 0.f, 0.f, 0.f};

    GEMM_KLOOP(A, Bt, K);

    const int cr = (lane >> 4) << 2;
#pragma unroll
    for (int i = 0; i < 4; i++)
#pragma unroll
        for (int j = 0; j < 4; j++) {
#pragma unroll
            for (int r = 0; r < 4; r++) {
                C[(size_t)(m0 + wr + i * 16 + cr + r) * N + n0 + wc + j * 16 +
                  fr] = acc[i][j][r];
            }
        }
}

// ---------------------------------------------------------------------------
// Gate GEMM fused with gated RMSNorm epilogue; o read as bf16.
// ---------------------------------------------------------------------------
__global__ void __launch_bounds__(256) gemm_gate_rms(
    const unsigned short* __restrict__ A, const unsigned short* __restrict__ Bt,
    const unsigned short* __restrict__ o, const float* __restrict__ rfac,
    const float* __restrict__ norm_w, unsigned short* __restrict__ out,
    int M, int N, int K) {
    GEMM_SHARED();
    const int tid = threadIdx.x;
    const int nbx = N >> 7;
    const int bx = blockIdx.x % nbx, by = blockIdx.x / nbx;
    const int m0 = by << 7, n0 = bx << 7;
    const int h = n0 >> 7;
    const int w = tid >> 6, lane = tid & 63;
    const int wr = (w >> 1) << 6, wc = (w & 1) << 6;
    const int fr = lane & 15, fk8 = (lane >> 4) << 3;
    const int grow = lane >> 2;
    const int gcol = (lane & 3) << 3;

    f32x4 acc[4][4];
#pragma unroll
    for (int i = 0; i < 4; i++)
#pragma unroll
        for (int j = 0; j < 4; j++)
            acc[i][j] = (f32x4){0.f, 0.f, 0.f, 0.f};

    GEMM_KLOOP(A, Bt, K);

    const int cr = (lane >> 4) << 2;
#pragma unroll
    for (int i = 0; i < 4; i++)
#pragma unroll
        for (int j = 0; j < 4; j++) {
            const int colh = wc + j * 16 + fr;
            const float nw = norm_w[colh];
#pragma unroll
            for (int r = 0; r < 4; r++) {
                const int row = m0 + wr + i * 16 + cr + r;
                float ov = bf2f(o[(size_t)row * VDIMc + n0 + colh]);
                float f = rfac[(size_t)row * Hc + h];
                float y = ov * f * nw * siluf(acc[i][j][r]);
                out[(size_t)row * VDIMc + n0 + colh] = f2bf(y);
            }
        }
}

// ---------------------------------------------------------------------------
// Per-(row,h) RMS factor from bf16 o: rf = rsqrt(mean(o^2)+eps).
// ---------------------------------------------------------------------------
__global__ void __launch_bounds__(256) rfac_kernel(
    const unsigned short* __restrict__ o, float* __restrict__ rf) {
    const int row = blockIdx.x * 4 + (threadIdx.x >> 6);
    const int lane = threadIdx.x & 63;
    const size_t base = (size_t)row * DVc;
    unsigned int pv = *(const unsigned int*)&o[base + lane * 2];
    float o0 = bf2f((unsigned short)(pv & 0xffff));
    float o1 = bf2f((unsigned short)(pv >> 16));
    float ss = o0 * o0 + o1 * o1;
#pragma unroll
    for (int m = 1; m < 64; m <<= 1) ss += __shfl_xor(ss, m, 64);
    if (lane == 0) rf[row] = rsqrtf(ss * (1.f / 128.f) + 1e-5f);
}

// ---------------------------------------------------------------------------
// a/b projections: transposed f32 weights, one wave per 4 rows.
// ---------------------------------------------------------------------------
__global__ void __launch_bounds__(256) ab_proj(
    const float* __restrict__ x, const float* __restrict__ w_aT,
    const float* __restrict__ w_bT, const float* __restrict__ A_log,
    const float* __restrict__ dt_bias, float* __restrict__ g_out,
    float* __restrict__ beta_out) {
    const int wv = threadIdx.x >> 6;
    const int lane = threadIdx.x & 63;
    const int h = lane >> 2, kg = lane & 3;
    const int row0 = blockIdx.x * 16 + wv * 4;
    const float* wa = w_aT + (size_t)h * Dc + kg * 256;
    const float* wb = w_bT + (size_t)h * Dc + kg * 256;
    const float* xr = x + (size_t)row0 * Dc + kg * 256;
    float pa[4] = {0.f, 0.f, 0.f, 0.f}, pb[4] = {0.f, 0.f, 0.f, 0.f};
#pragma unroll 4
    for (int k = 0; k < 256; k += 4) {
        float4 a4 = *(const float4*)&wa[k];
        float4 b4 = *(const float4*)&wb[k];
#pragma unroll
        for (int r = 0; r < 4; r++) {
            float4 x4 = *(const float4*)&xr[(size_t)r * Dc + k];
            pa[r] += dot4(x4, a4);
            pb[r] += dot4(x4, b4);
        }
    }
#pragma unroll
    for (int r = 0; r < 4; r++) {
        pa[r] += __shfl_xor(pa[r], 1, 64);
        pa[r] += __shfl_xor(pa[r], 2, 64);
        pb[r] += __shfl_xor(pb[r], 1, 64);
        pb[r] += __shfl_xor(pb[r], 2, 64);
    }
    if (kg == 0) {
        const float el = __expf(A_log[h]);
        const float db = dt_bias[h];
#pragma unroll
        for (int r = 0; r < 4; r++) {
            float arg = pa[r] + db;
            float sp = fmaxf(arg, 0.f) + log1pf(__expf(-fabsf(arg)));
            g_out[(size_t)(row0 + r) * Hc + h] = -el * sp;
            beta_out[(size_t)(row0 + r) * Hc + h] =
                2.f / (1.f + __expf(-pb[r]));
        }
    }
}

// ---------------------------------------------------------------------------
// Save 3-row halos at 64-step chunk boundaries (for in-place v conv).
// ---------------------------------------------------------------------------
template <int C>
__global__ void __launch_bounds__(256) save_halo(
    const float* __restrict__ in, float* __restrict__ halo) {
    const int g = blockIdx.x * 256 + threadIdx.x;
    const int total = Bc * (Tc / 64 - 1) * 3 * C;
    if (g >= total) return;
    const int c = g % C;
    int r = g / C;
    const int j = r % 3;
    r /= 3;
    const int chunk = r % (Tc / 64 - 1) + 1;
    const int b = r / (Tc / 64 - 1);
    halo[((size_t)(b * 64 + chunk) * 3 + j) * C + c] =
        in[((size_t)b * Tc + chunk * 64 - 3 + j) * C + c];
}

// ---------------------------------------------------------------------------
// Fused q+k depthwise causal conv1d + SiLU + l2norm, bf16->bf16.
// ---------------------------------------------------------------------------
__global__ void __launch_bounds__(256) conv_qk(
    const unsigned short* __restrict__ qin, const float* __restrict__ wq,
    unsigned short* __restrict__ qout, const unsigned short* __restrict__ kin,
    const float* __restrict__ wk, unsigned short* __restrict__ kout) {
    constexpr int C = KDIMc;
    constexpr int CB = C / 256;
    const int half = Bc * (Tc / 64) * CB;
    int bidx = blockIdx.x;
    const unsigned short* in;
    const float* w;
    unsigned short* out;
    if (bidx < half) { in = qin; w = wq; out = qout; }
    else { bidx -= half; in = kin; w = wk; out = kout; }
    const int cb = bidx % CB;
    const int tchunk = (bidx / CB) % (Tc / 64);
    const int b = bidx / (CB * (Tc / 64));
    const int c = cb * 256 + threadIdx.x;
    const int t0 = tchunk * 64;
    const float w0 = w[c * 4 + 0], w1 = w[c * 4 + 1], w2 = w[c * 4 + 2],
                w3 = w[c * 4 + 3];
    const unsigned short* src = in + (size_t)b * Tc * C + c;
    float xm3 = (t0 >= 3) ? bf2f(src[(size_t)(t0 - 3) * C]) : 0.f;
    float xm2 = (t0 >= 2) ? bf2f(src[(size_t)(t0 - 2) * C]) : 0.f;
    float xm1 = (t0 >= 1) ? bf2f(src[(size_t)(t0 - 1) * C]) : 0.f;
    unsigned short* dst = out + (size_t)b * Tc * C + c;
#pragma unroll 4
    for (int i = 0; i < 64; i++) {
        float xt = bf2f(src[(size_t)(t0 + i) * C]);
        float y = w0 * xm3 + w1 * xm2 + w2 * xm1 + w3 * xt;
        y = siluf(y);
        {
            float ss = y * y;
#pragma unroll
            for (int m = 1; m < 64; m <<= 1) ss += __shfl_xor(ss, m, 64);
            y *= rsqrtf(ss + 1e-6f);
        }
        dst[(size_t)(t0 + i) * C] = f2bf(y);
        xm3 = xm2;
        xm2 = xm1;
        xm1 = xt;
    }
}

// ---------------------------------------------------------------------------
// Depthwise causal conv1d (K=4) + SiLU, IN PLACE f32 (for v).
// ---------------------------------------------------------------------------
template <int C, bool L2N>
__global__ void __launch_bounds__(256) conv_silu_inplace(
    float* __restrict__ buf, const float* __restrict__ w,
    const float* __restrict__ halo) {
    constexpr int CB = C / 256;
    const int bidx = blockIdx.x;
    const int cb = bidx % CB;
    const int tchunk = (bidx / CB) % (Tc / 64);
    const int b = bidx / (CB * (Tc / 64));
    const int c = cb * 256 + threadIdx.x;
    const int t0 = tchunk * 64;
    const float w0 = w[c * 4 + 0], w1 = w[c * 4 + 1], w2 = w[c * 4 + 2],
                w3 = w[c * 4 + 3];
    float xm3 = 0.f, xm2 = 0.f, xm1 = 0.f;
    if (tchunk > 0) {
        const float* hp = halo + (size_t)(b * 64 + tchunk) * 3 * C + c;
        xm3 = hp[0];
        xm2 = hp[C];
        xm1 = hp[2 * C];
    }
    float* p = buf + (size_t)b * Tc * C + c;
#pragma unroll 4
    for (int i = 0; i < 64; i++) {
        float xt = p[(size_t)(t0 + i) * C];
        float y = w0 * xm3 + w1 * xm2 + w2 * xm1 + w3 * xt;
        y = siluf(y);
        if (L2N) {
            float ss = y * y;
#pragma unroll
            for (int m = 1; m < 64; m <<= 1) ss += __shfl_xor(ss, m, 64);
            y *= rsqrtf(ss + 1e-6f);
        }
        p[(size_t)(t0 + i) * C] = y;
        xm3 = xm2;
        xm2 = xm1;
        xm1 = xt;
    }
}

// ---------------------------------------------------------------------------
// TM precompute: Gram via bf16 MFMA, f32 solve (readlane broadcast).
// T,M stored bf16 [t][s].
// ---------------------------------------------------------------------------
__global__ void __launch_bounds__(256) tm_precompute(
    const unsigned short* __restrict__ kc, const unsigned short* __restrict__ qc,
    const float* __restrict__ g, const float* __restrict__ beta,
    unsigned short* __restrict__ tmT, unsigned short* __restrict__ tmM) {
    const int bid = blockIdx.x;
    const int ch = bid & (NCH - 1);
    const int bh = bid >> 6;
    const int b = bh >> 4, h = bh & 15;
    const int tid = threadIdx.x;
    const int t0 = ch * CC;

    __shared__ __align__(16) unsigned short kb16[CC][72];
    __shared__ __align__(16) unsigned short qb16[CC][72];
    __shared__ __align__(16) float AtL[CC][DKc + 4];  // A^T: AtL[s][t]
    __shared__ float cL[CC], betaL[CC];

    const size_t qk0 = (size_t)b * Tc * KDIMc + h * DKc;
    const size_t gb0 = (size_t)b * Tc * Hc + h;
    const size_t tile = (size_t)(bh * NCH + ch) * 4096;

#pragma unroll
    for (int i = 0; i < 2; i++) {
        int e = tid + i * 256;
        int r = e >> 3, c8 = (e & 7) << 3;
        *(short8*)&kb16[r][c8] =
            *(const short8*)&kc[qk0 + (size_t)(t0 + r) * KDIMc + c8];
        *(short8*)&qb16[r][c8] =
            *(const short8*)&qc[qk0 + (size_t)(t0 + r) * KDIMc + c8];
    }
    if (tid < 64) {
        float gv = g[gb0 + (size_t)(t0 + tid) * Hc];
        float cv = gv;
#pragma unroll
        for (int d = 1; d < 64; d <<= 1) {
            float nb = __shfl_up(cv, d, 64);
            if (tid >= d) cv += nb;
        }
        cL[tid] = cv;
        betaL[tid] = beta[gb0 + (size_t)(t0 + tid) * Hc];
    }
    __syncthreads();

    {
        const int w = tid >> 6, lane = tid & 63;
        const int fr = lane & 15, fk8 = (lane >> 4) << 3;
        const int rr = (lane >> 4) << 2;
        short8 ak0 = *(const short8*)&kb16[w * 16 + fr][fk8];
        short8 ak1 = *(const short8*)&kb16[w * 16 + fr][fk8 + 32];
        short8 aq0 = *(const short8*)&qb16[w * 16 + fr][fk8];
        short8 aq1 = *(const short8*)&qb16[w * 16 + fr][fk8 + 32];
#pragma unroll
        for (int j = 0; j < 4; j++) {
            short8 b0 = *(const short8*)&kb16[j * 16 + fr][fk8];
            short8 b1 = *(const short8*)&kb16[j * 16 + fr][fk8 + 32];
            f32x4 kk = (f32x4){0.f, 0.f, 0.f, 0.f};
            f32x4 qk = (f32x4){0.f, 0.f, 0.f, 0.f};
            kk = __builtin_amdgcn_mfma_f32_16x16x32_bf16(ak0, b0, kk, 0, 0, 0);
            kk = __builtin_amdgcn_mfma_f32_16x16x32_bf16(ak1, b1, kk, 0, 0, 0);
            qk = __builtin_amdgcn_mfma_f32_16x16x32_bf16(aq0, b0, qk, 0, 0, 0);
            qk = __builtin_amdgcn_mfma_f32_16x16x32_bf16(aq1, b1, qk, 0, 0, 0);
#pragma unroll
            for (int r = 0; r < 4; r++) {
                int t = w * 16 + rr + r, s = j * 16 + fr;
                float E = (s <= t) ? __expf(cL[t] - cL[s]) : 0.f;
                AtL[s][t] = (s < t) ? betaL[t] * E * kk[r] : 0.f;
                tmM[tile + (size_t)t * 64 + s] =
                    (s <= t) ? f2bf(0.125f * E * qk[r]) : (unsigned short)0;
            }
        }
    }
    __syncthreads();

    {
        const int w = tid >> 6, lane = tid & 63;
        float acc[16];
#pragma unroll
        for (int di = 0; di < 16; di++)
            acc[di] = (lane == w * 16 + di) ? 1.f : 0.f;
        // Forward substitution, fully unrolled; readlane broadcast (SALU).
#pragma unroll
        for (int s = 0; s < 64; s++) {
            float a = AtL[s][lane];
            float ds[16];
#pragma unroll
            for (int di = 0; di < 16; di++)
                ds[di] = __uint_as_float(
                    __builtin_amdgcn_readlane(__float_as_uint(acc[di]), s));
#pragma unroll
            for (int di = 0; di < 16; di++)
                acc[di] = fmaf(-a, ds[di], acc[di]);
        }
        unsigned short tb[16];
#pragma unroll
        for (int di = 0; di < 16; di++) tb[di] = f2bf(acc[di]);
        *(uint4*)&tmT[tile + (size_t)lane * 64 + w * 16] = *(uint4*)&tb[0];
        *(uint4*)&tmT[tile + (size_t)lane * 64 + w * 16 + 8] = *(uint4*)&tb[8];
    }
}

// ---------------------------------------------------------------------------
// Sequential chunk scan (R19-proven): conflict-free K^T staging, all-MFMA
// phases, register-resident S, V read f32, O stored bf16. 8-way DV split.
// ---------------------------------------------------------------------------
__global__ void __launch_bounds__(512, 2) delta_scan(
    const unsigned short* __restrict__ kc, const unsigned short* __restrict__ qc,
    const unsigned short* __restrict__ kcT,  // [B][KDIM][T]
    const float* __restrict__ vc, unsigned short* __restrict__ o16,
    const float* __restrict__ g, const float* __restrict__ beta,
    const unsigned short* __restrict__ tmT,
    const unsigned short* __restrict__ tmM) {
    const int bid = blockIdx.x;
    const int sl = bid >> 5;   // 0..7
    const int bh = bid & 31;   // 0..31 -> XCD = bh%8
    const int b = bh >> 4, h = bh & 15;
    const int tid = threadIdx.x;

    __shared__ __align__(16) float VL[CC][20];
    __shared__ float gamL[CC], egL[CC], betaL[CC];
    __shared__ __align__(16) unsigned short kb16[CC][72];  // K rows
    __shared__ __align__(16) unsigned short kh16[CC][72];  // K^T: [dk][t]
    __shared__ __align__(16) unsigned short qb16[CC][72];
    __shared__ __align__(16) unsigned short Tb16[CC][72];
    __shared__ __align__(16) unsigned short Mb16[CC][72];
    __shared__ __align__(16) unsigned short STb16[16][72];  // S^T bf16 copy
    __shared__ __align__(16) unsigned short DTb16[16][72];  // RHS^T bf16
    __shared__ __align__(16) unsigned short D2b16[16][72];  // delta^T bf16
    __shared__ __align__(16) unsigned short egd16[16][72];  // (eg*delta)^T

    const size_t qk0 = (size_t)b * Tc * KDIMc + h * DKc;
    const size_t kT0 = ((size_t)b * KDIMc + h * DKc) * Tc;
    const size_t v0 = (size_t)b * Tc * VDIMc + h * DVc + sl * 16;
    const size_t gb0 = (size_t)b * Tc * Hc + h;
    const size_t tb0 = (size_t)(bh * NCH) * 4096;

    for (int i = tid; i < 16 * 72; i += 512) ((unsigned short*)STb16)[i] = 0;

    const int r8 = tid >> 3, c8 = (tid & 7) << 3;  // bf16 staging coords
    const int wid = tid >> 6, lane = tid & 63;
    const int fr = lane & 15;
    const int fk8 = (lane >> 4) << 3;
    const int rr = (lane >> 4) << 2;

    f32x4 accS = (f32x4){0.f, 0.f, 0.f, 0.f};  // waves 0-3: S[w*16+rr+r][fr]

    short8 kv, kvT, qv, tv, mv;
    float4 vv0;
    float gvr = 0.f, bvr = 0.f;

#define LOADREGS(CH)                                                          \
    {                                                                         \
        const size_t tK = qk0 + (size_t)(CH) * CC * KDIMc;                    \
        const size_t tile_ = tb0 + (size_t)(CH) * 4096;                       \
        kv = *(const short8*)&kc[tK + (size_t)r8 * KDIMc + c8];               \
        kvT = *(const short8*)&kcT[kT0 + (size_t)r8 * Tc + (CH) * CC + c8];   \
        qv = *(const short8*)&qc[tK + (size_t)r8 * KDIMc + c8];               \
        tv = *(const short8*)&tmT[tile_ + (size_t)tid * 8];                   \
        mv = *(const short8*)&tmM[tile_ + (size_t)tid * 8];                   \
        if (tid < 256)                                                        \
            vv0 = *(const float4*)&vc[v0 +                                    \
                                      (size_t)((CH) * CC + (tid >> 2)) *     \
                                          VDIMc +                             \
                                      ((tid & 3) << 2)];                      \
        if (tid < 64) {                                                       \
            gvr = g[gb0 + (size_t)((CH) * CC + tid) * Hc];                    \
            bvr = beta[gb0 + (size_t)((CH) * CC + tid) * Hc];                 \
        }                                                                     \
    }

    LOADREGS(0);

#pragma unroll 1
    for (int ch = 0; ch < NCH; ch++) {
        __syncthreads();  // B0: prev chunk fully done (STb16 visible)

        // ---- stage regs -> LDS (pure short8 copies; no conversions)
        {
            *(short8*)&kb16[r8][c8] = kv;
            *(short8*)&kh16[r8][c8] = kvT;
            *(short8*)&qb16[r8][c8] = qv;
            *(short8*)&Tb16[r8][c8] = tv;
            *(short8*)&Mb16[r8][c8] = mv;
            if (tid < 256) *(float4*)&VL[tid >> 2][(tid & 3) << 2] = vv0;
            if (tid < 64) {
                float cv = gvr;
#pragma unroll
                for (int d = 1; d < 64; d <<= 1) {
                    float nb = __shfl_up(cv, d, 64);
                    if (tid >= d) cv += nb;
                }
                gamL[tid] = __expf(cv);
                float cend = __shfl(cv, 63, 64);
                egL[tid] = __expf(cend - cv);
                betaL[tid] = bvr;
            }
        }
        if (ch + 1 < NCH) LOADREGS(ch + 1);
        __syncthreads();  // B1: stage visible

        // ---- phase 1: KS (waves 0-3) and QS (waves 4-7) via MFMA
        f32x4 acc1 = (f32x4){0.f, 0.f, 0.f, 0.f};
        {
            short8 bs0 = *(const short8*)&STb16[fr][fk8];
            short8 bs1 = *(const short8*)&STb16[fr][fk8 + 32];
            if (wid < 4) {
                const int m0 = wid << 4;
                short8 a0 = *(const short8*)&kb16[m0 + fr][fk8];
                short8 a1 = *(const short8*)&kb16[m0 + fr][fk8 + 32];
                acc1 = __builtin_amdgcn_mfma_f32_16x16x32_bf16(a0, bs0, acc1, 0, 0, 0);
                acc1 = __builtin_amdgcn_mfma_f32_16x16x32_bf16(a1, bs1, acc1, 0, 0, 0);
#pragma unroll
                for (int r = 0; r < 4; r++) {
                    int t = m0 + rr + r;
                    float rhs = betaL[t] * (VL[t][fr] - gamL[t] * acc1[r]);
                    DTb16[fr][t] = f2bf(rhs);
                }
            } else {
                const int m0 = (wid - 4) << 4;
                short8 a0 = *(const short8*)&qb16[m0 + fr][fk8];
                short8 a1 = *(const short8*)&qb16[m0 + fr][fk8 + 32];
                acc1 = __builtin_amdgcn_mfma_f32_16x16x32_bf16(a0, bs0, acc1, 0, 0, 0);
                acc1 = __builtin_amdgcn_mfma_f32_16x16x32_bf16(a1, bs1, acc1, 0, 0, 0);
#pragma unroll
                for (int r = 0; r < 4; r++) {
                    int t = m0 + rr + r;
                    acc1[r] *= 0.125f * gamL[t];
                }
            }
        }
        __syncthreads();  // B2: RHS ready

        // ---- phase 2: delta = T * RHS (waves 0-3); write delta and eg*delta
        if (wid < 4) {
            const int m0 = wid << 4;
            short8 a0 = *(const short8*)&Tb16[m0 + fr][fk8];
            short8 a1 = *(const short8*)&Tb16[m0 + fr][fk8 + 32];
            short8 b0 = *(const short8*)&DTb16[fr][fk8];
            short8 b1 = *(const short8*)&DTb16[fr][fk8 + 32];
            f32x4 d = (f32x4){0.f, 0.f, 0.f, 0.f};
            d = __builtin_amdgcn_mfma_f32_16x16x32_bf16(a0, b0, d, 0, 0, 0);
            d = __builtin_amdgcn_mfma_f32_16x16x32_bf16(a1, b1, d, 0, 0, 0);
#pragma unroll
            for (int r = 0; r < 4; r++) {
                int t = m0 + rr + r;
                D2b16[fr][t] = f2bf(d[r]);
                egd16[fr][t] = f2bf(egL[t] * d[r]);
            }
        }
        __syncthreads();  // B3: delta ready

        // ---- phase 3 (waves 4-7): O = M*delta + scaledQS, store bf16.
        //      phase 4 (waves 0-3): S = ge*S + K^T(eg*delta) via MFMA.
        if (wid >= 4) {
            const int m0 = (wid - 4) << 4;
            short8 a0 = *(const short8*)&Mb16[m0 + fr][fk8];
            short8 a1 = *(const short8*)&Mb16[m0 + fr][fk8 + 32];
            short8 b0 = *(const short8*)&D2b16[fr][fk8];
            short8 b1 = *(const short8*)&D2b16[fr][fk8 + 32];
            f32x4 o = acc1;  // 0.125*gam*QS
            o = __builtin_amdgcn_mfma_f32_16x16x32_bf16(a0, b0, o, 0, 0, 0);
            o = __builtin_amdgcn_mfma_f32_16x16x32_bf16(a1, b1, o, 0, 0, 0);
#pragma unroll
            for (int r = 0; r < 4; r++)
                o16[v0 + (size_t)(ch * CC + m0 + rr + r) * VDIMc + fr] =
                    f2bf(o[r]);
        } else {
            const int m0 = wid << 4;
            const float ge = gamL[63];
            short8 a0 = *(const short8*)&kh16[m0 + fr][fk8];
            short8 a1 = *(const short8*)&kh16[m0 + fr][fk8 + 32];
            short8 b0 = *(const short8*)&egd16[fr][fk8];
            short8 b1 = *(const short8*)&egd16[fr][fk8 + 32];
#pragma unroll
            for (int r = 0; r < 4; r++) accS[r] *= ge;
            accS = __builtin_amdgcn_mfma_f32_16x16x32_bf16(a0, b0, accS, 0, 0, 0);
            accS = __builtin_amdgcn_mfma_f32_16x16x32_bf16(a1, b1, accS, 0, 0, 0);
#pragma unroll
            for (int r = 0; r < 4; r++)
                STb16[fr][m0 + rr + r] = f2bf(accS[r]);
        }
    }
#undef LOADREGS
}

// ---------------------------------------------------------------------------
// Workspace (floats), 236 MB (R18/R19-proven layout):
//   qb 8.39M (q16raw -> kcT16) | kb 8.39M (k16raw -> o16) | vb 16.78M f32 |
//   tm-region 16.78M (tmT16|tmM16|qc16|kc16 shorts; halo aliases start) |
//   gbuf | bbuf | xtra.  obb aliases tm start (after scan); rfac = gbuf.
// ---------------------------------------------------------------------------
extern "C" void kernel_launch(void* const* d_in, const int* in_sizes, int n_in,
                              void* d_out, int out_size, void* d_ws,
                              size_t ws_size, hipStream_t stream) {
    const float* x = (const float*)d_in[0];
    const float* w_q = (const float*)d_in[1];
    const float* w_k = (const float*)d_in[2];
    const float* w_v = (const float*)d_in[3];
    const float* w_a = (const float*)d_in[4];
    const float* w_b = (const float*)d_in[5];
    const float* w_g = (const float*)d_in[6];
    const float* w_out = (const float*)d_in[7];
    const float* A_log = (const float*)d_in[8];
    const float* dt_bias = (const float*)d_in[9];
    const float* conv_q = (const float*)d_in[10];
    const float* conv_k = (const float*)d_in[11];
    const float* conv_v = (const float*)d_in[12];
    const float* norm_w = (const float*)d_in[13];

    float* ws = (float*)d_ws;
    const size_t M = Mrows;
    float* qb = ws;
    float* kb = qb + M * KDIMc;
    float* vb = kb + M * KDIMc;
    float* tm = vb + M * VDIMc;          // 16.78M floats region
    float* gbuf = tm + M * VDIMc;
    float* bbuf = gbuf + M * Hc;
    float* xtra = bbuf + M * Hc;

    unsigned short* q16raw = (unsigned short*)qb;
    unsigned short* k16raw = (unsigned short*)kb;
    unsigned short* kcT16 = (unsigned short*)qb;  // alias: after conv_q
    unsigned short* o16 = (unsigned short*)kb;    // alias: after conv_k
    unsigned short* tmS = (unsigned short*)tm;
    unsigned short* tmT16 = tmS;
    unsigned short* tmM16 = tmS + (size_t)8388608;
    unsigned short* qc16 = tmS + (size_t)16777216;
    unsigned short* kc16 = tmS + (size_t)25165824;
    float* halo = tm;                     // dead before tm_precompute
    unsigned short* obb = tmS;            // after scan, tmT/tmM dead
    float* rfac = gbuf;                   // g dead after scan

    unsigned short* xb = (unsigned short*)xtra;
    unsigned short* wqT = xb + M * KDIMc;
    unsigned short* wkT = wqT + (size_t)KDIMc * Dc;
    unsigned short* wvT = wkT + (size_t)KDIMc * Dc;  // wqT|wkT|wvT contiguous
    unsigned short* wgT = wvT + (size_t)VDIMc * Dc;
    unsigned short* woT = wgT + (size_t)VDIMc * Dc;
    float* waT = (float*)(woT + (size_t)Dc * VDIMc);
    float* wbT = waT + (size_t)16 * Dc;

    // 0) fused prep: weight transposes + a/b transposes + x convert
    prep_all<<<dim3(1024 + 1024 + 2048 + 2048 + 2048 + 16 + 16 + 8192), 256,
               0, stream>>>(x, w_q, w_k, w_v, w_g, w_out, w_a, w_b, xb, wqT,
                            wkT, wvT, wgT, woT, waT, wbT);

    // 1) fused q/k/v projection (one GEMM, BK=64; q/k out bf16, v f32)
    gemm_qkv<<<dim3((M / 128) * 32), 256, 0, stream>>>(xb, wqT, q16raw, k16raw,
                                                       vb);

    // 2) a/b projections -> g, beta
    ab_proj<<<dim3(M / 16), 256, 0, stream>>>(x, waT, wbT, A_log, dt_bias,
                                              gbuf, bbuf);

    // 3) conv + silu: fused q+k bf16->bf16 (+l2norm); v in-place f32
    conv_qk<<<dim3(2 * Bc * (Tc / 64) * (KDIMc / 256)), 256, 0, stream>>>(
        q16raw, conv_q, qc16, k16raw, conv_k, kc16);
    // kcT16 = kc16 transposed to [B][KDIM][T] (aliases qb; conv_q done)
    transp_k16<<<dim3(Bc * 16 * 64), 256, 0, stream>>>(kc16, kcT16);
    {
        const int nv = Bc * (Tc / 64 - 1) * 3 * VDIMc;
        save_halo<VDIMc><<<dim3((nv + 255) / 256), 256, 0, stream>>>(vb, halo);
        conv_silu_inplace<VDIMc, false>
            <<<dim3(Bc * (Tc / 64) * (VDIMc / 256)), 256, 0, stream>>>(
                vb, conv_v, halo);
    }

    // 4a) parallel precompute of T=(I+A)^{-1} and M (bf16 out)
    tm_precompute<<<dim3(Bc * Hc * NCH), 256, 0, stream>>>(
        kc16, qc16, gbuf, bbuf, tmT16, tmM16);
    // 4b) sequential scan (8-way DV split, R19-proven)
    delta_scan<<<dim3(Bc * Hc * 8), 512, 0, stream>>>(
        kc16, qc16, kcT16, vb, o16, gbuf, bbuf, tmT16, tmM16);

    // 5) rms factors from bf16 o, then gate GEMM fused with rms epilogue
    rfac_kernel<<<dim3(M * Hc / 4), 256, 0, stream>>>(o16, rfac);
    gemm_gate_rms<<<dim3((M / 128) * (VDIMc / 128)), 256, 0, stream>>>(
        xb, wgT, o16, rfac, norm_w, obb, M, VDIMc, Dc);

    // 6) output projection (bf16 MFMA, BK=64) -> d_out
    gemm_bf16<<<dim3((M / 128) * (Dc / 128)), 256, 0, stream>>>(
        obb, woT, (float*)d_out, M, Dc, VDIMc);
}

// Round 27
// 486.487 us; speedup vs baseline: 1.0777x; 1.0202x over previous
//
#include <hip/hip_runtime.h>
#include <hip/hip_bf16.h>
#include <math.h>

// Problem constants
#define Bc 2
#define Tc 4096
#define Dc 1024
#define Hc 16
#define DKc 64
#define DVc 128
#define KDIMc 1024   // H*DK
#define VDIMc 2048   // H*DV
#define Mrows (Bc*Tc) // 8192
#define CC 64        // scan chunk size
#define NCH (Tc/CC)  // 64 chunks

typedef short short8 __attribute__((ext_vector_type(8)));
typedef float f32x4 __attribute__((ext_vector_type(4)));

__device__ __forceinline__ float siluf(float x) {
    return x / (1.f + __expf(-x));
}
__device__ __forceinline__ float dot4(float4 a, float4 b) {
    return a.x * b.x + a.y * b.y + a.z * b.z + a.w * b.w;
}
__device__ __forceinline__ unsigned short f2bf(float f) {
    unsigned int u = __float_as_uint(f);
    unsigned int r = (u + 0x7fffu + ((u >> 16) & 1u)) >> 16;
    return (unsigned short)r;
}
__device__ __forceinline__ unsigned int pk2(float a, float b) {
    return (unsigned)f2bf(a) | ((unsigned)f2bf(b) << 16);
}
__device__ __forceinline__ float bf2f(unsigned short s) {
    unsigned int u = ((unsigned int)s) << 16;
    return __uint_as_float(u);
}
// async global->LDS DMA, 16B per lane; lds base must be wave-uniform.
__device__ __forceinline__ void gload16(const unsigned short* g,
                                        unsigned short* l) {
    __builtin_amdgcn_global_load_lds(
        (const __attribute__((address_space(1))) unsigned int*)g,
        (__attribute__((address_space(3))) unsigned int*)l, 16, 0, 0);
}

// ---------------------------------------------------------------------------
// Fused prep kernel: 5 bf16 weight transposes + 2 f32 a/b transposes +
// x f32->bf16 convert, dispatched by blockIdx range (provably disjoint).
// ---------------------------------------------------------------------------
__device__ void tile_transp_bf16(const float* __restrict__ in,
                                 unsigned short* __restrict__ out, int K,
                                 int N, int blk) {
    __shared__ float t[32][33];
    const int nbx = N >> 5;
    const int n0 = (blk % nbx) << 5;
    const int k0 = (blk / nbx) << 5;
    const int c = threadIdx.x & 31, r4 = (threadIdx.x >> 5) << 2;
#pragma unroll
    for (int i = 0; i < 4; i++)
        t[r4 + i][c] = in[(size_t)(k0 + r4 + i) * N + n0 + c];
    __syncthreads();
#pragma unroll
    for (int i = 0; i < 4; i++)
        out[(size_t)(n0 + r4 + i) * K + k0 + c] = f2bf(t[c][r4 + i]);
}

__device__ void tile_transp_f32w(const float* __restrict__ in,
                                 float* __restrict__ out, int blk) {
    __shared__ float t2[64][17];
    const int k0 = blk * 64;
    const int r = threadIdx.x >> 2, c4 = (threadIdx.x & 3) << 2;
    float4 v = *(const float4*)&in[(size_t)(k0 + r) * 16 + c4];
    t2[r][c4 + 0] = v.x;
    t2[r][c4 + 1] = v.y;
    t2[r][c4 + 2] = v.z;
    t2[r][c4 + 3] = v.w;
    __syncthreads();
    const int n = threadIdx.x >> 4;
    const int kk = (threadIdx.x & 15) << 2;
    out[(size_t)n * Dc + k0 + kk + 0] = t2[kk + 0][n];
    out[(size_t)n * Dc + k0 + kk + 1] = t2[kk + 1][n];
    out[(size_t)n * Dc + k0 + kk + 2] = t2[kk + 2][n];
    out[(size_t)n * Dc + k0 + kk + 3] = t2[kk + 3][n];
}

__global__ void __launch_bounds__(256) prep_all(
    const float* __restrict__ x, const float* __restrict__ w_q,
    const float* __restrict__ w_k, const float* __restrict__ w_v,
    const float* __restrict__ w_g, const float* __restrict__ w_out,
    const float* __restrict__ w_a, const float* __restrict__ w_b,
    unsigned short* __restrict__ xb, unsigned short* __restrict__ wqT,
    unsigned short* __restrict__ wkT, unsigned short* __restrict__ wvT,
    unsigned short* __restrict__ wgT, unsigned short* __restrict__ woT,
    float* __restrict__ waT, float* __restrict__ wbT) {
    int blk = blockIdx.x;
    if (blk < 1024) { tile_transp_bf16(w_q, wqT, Dc, KDIMc, blk); return; }
    blk -= 1024;
    if (blk < 1024) { tile_transp_bf16(w_k, wkT, Dc, KDIMc, blk); return; }
    blk -= 1024;
    if (blk < 2048) { tile_transp_bf16(w_v, wvT, Dc, VDIMc, blk); return; }
    blk -= 2048;
    if (blk < 2048) { tile_transp_bf16(w_g, wgT, Dc, VDIMc, blk); return; }
    blk -= 2048;
    if (blk < 2048) { tile_transp_bf16(w_out, woT, VDIMc, Dc, blk); return; }
    blk -= 2048;
    if (blk < 16) { tile_transp_f32w(w_a, waT, blk); return; }
    blk -= 16;
    if (blk < 16) { tile_transp_f32w(w_b, wbT, blk); return; }
    blk -= 16;
    // x convert: 8192 blocks, 4 floats/thread
    int g = blk * 256 + threadIdx.x;
    float4 v = *(const float4*)&x[(size_t)g * 4];
    *(uint2*)&xb[(size_t)g * 4] = make_uint2(pk2(v.x, v.y), pk2(v.z, v.w));
}

// ---------------------------------------------------------------------------
// bf16 tile transpose: in [B][T][KDIM] -> out [B][KDIM][T]. 64x64 tiles.
// ---------------------------------------------------------------------------
__global__ void __launch_bounds__(256) transp_k16(
    const unsigned short* __restrict__ in, unsigned short* __restrict__ out) {
    __shared__ unsigned short t[64][68];  // 136B rows (8B-aligned)
    const int bx = blockIdx.x & 63;          // t-block
    const int by = (blockIdx.x >> 6) & 15;   // c-block (KDIM/64)
    const int b = blockIdx.x >> 10;
    const int t0 = bx << 6, c0 = by << 6;
    {
        const int row = threadIdx.x >> 2, c16 = (threadIdx.x & 3) << 4;
        const unsigned short* src =
            &in[((size_t)b * Tc + t0 + row) * KDIMc + c0 + c16];
#pragma unroll
        for (int i = 0; i < 4; i++)
            *(uint2*)&t[row][c16 + i * 4] = *(const uint2*)&src[i * 4];
    }
    __syncthreads();
    {
        const int cc = threadIdx.x & 63, tp = (threadIdx.x >> 6) << 4;
        unsigned short v[16];
#pragma unroll
        for (int i = 0; i < 16; i++) v[i] = t[tp + i][cc];
        unsigned short* dst =
            &out[((size_t)b * KDIMc + c0 + cc) * Tc + t0 + tp];
        *(uint4*)&dst[0] = *(uint4*)&v[0];
        *(uint4*)&dst[8] = *(uint4*)&v[8];
    }
}

// ---------------------------------------------------------------------------
// GEMM building blocks, BK=64, counted-vmcnt double-buffered pipeline (T4):
// per K-step, issue next-tile global_load_lds into buf^1, then ONE fused
// asm {s_waitcnt vmcnt(8); s_barrier} (memory clobber: nothing crosses) --
// my 8 OLDER loads (current tile) are complete, the 8 newest (prefetch)
// stay in flight ACROSS the barrier; then ds_read+MFMA current buf; then
// {s_waitcnt lgkmcnt(0); s_barrier} so all reads drain before any wave
// overwrites this buffer two steps later. RAW: vmcnt(8)+barrier covers all
// waves' current-tile loads. WAR: writes to a buffer are issued only after
// the post-MFMA barrier that ended its reads. K-order per output element
// identical to the proven 2-barrier schedule => bit-identical results.
// ---------------------------------------------------------------------------
#define GEMM_SHARED()                                                         \
    __shared__ unsigned short As0[2][128 * 32], As1[2][128 * 32];             \
    __shared__ unsigned short Bs0[2][128 * 32], Bs1[2][128 * 32];

#define GEMM_STAGE64(Ap, Bp, Kk, KT, PB)                                      \
    {                                                                         \
        const size_t kb0 = (size_t)((KT) << 6) + gcol;                        \
        const size_t kb1 = kb0 + 32;                                          \
        _Pragma("unroll") for (int r = 0; r < 2; r++) {                       \
            const int rows = r * 64 + w * 16;                                 \
            gload16(&Ap[(size_t)(m0 + rows + grow) * Kk + kb0],               \
                    &As0[PB][rows * 32]);                                     \
            gload16(&Ap[(size_t)(m0 + rows + grow) * Kk + kb1],               \
                    &As1[PB][rows * 32]);                                     \
            gload16(&Bp[(size_t)(n0 + rows + grow) * Kk + kb0],               \
                    &Bs0[PB][rows * 32]);                                     \
            gload16(&Bp[(size_t)(n0 + rows + grow) * Kk + kb1],               \
                    &Bs1[PB][rows * 32]);                                     \
        }                                                                     \
    }

#define GEMM_MFMA64(PB)                                                       \
    {                                                                         \
        short8 af[4], bfr[4];                                                 \
        _Pragma("unroll") for (int i = 0; i < 4; i++)                         \
            af[i] = *(const short8*)&As0[PB][(wr + i * 16 + fr) * 32 + fk8];  \
        _Pragma("unroll") for (int j = 0; j < 4; j++)                         \
            bfr[j] = *(const short8*)&Bs0[PB][(wc + j * 16 + fr) * 32 + fk8]; \
        _Pragma("unroll") for (int i = 0; i < 4; i++)                         \
            _Pragma("unroll") for (int j = 0; j < 4; j++)                     \
                acc[i][j] = __builtin_amdgcn_mfma_f32_16x16x32_bf16(          \
                    af[i], bfr[j], acc[i][j], 0, 0, 0);                       \
        _Pragma("unroll") for (int i = 0; i < 4; i++)                         \
            af[i] = *(const short8*)&As1[PB][(wr + i * 16 + fr) * 32 + fk8];  \
        _Pragma("unroll") for (int j = 0; j < 4; j++)                         \
            bfr[j] = *(const short8*)&Bs1[PB][(wc + j * 16 + fr) * 32 + fk8]; \
        _Pragma("unroll") for (int i = 0; i < 4; i++)                         \
            _Pragma("unroll") for (int j = 0; j < 4; j++)                     \
                acc[i][j] = __builtin_amdgcn_mfma_f32_16x16x32_bf16(          \
                    af[i], bfr[j], acc[i][j], 0, 0, 0);                       \
    }

#define GEMM_KLOOP(Ap, Bp, Kk)                                                \
    {                                                                         \
        const int nkt = (Kk) >> 6;                                            \
        GEMM_STAGE64(Ap, Bp, Kk, 0, 0);                                       \
        for (int kt = 0; kt < nkt; kt++) {                                    \
            if (kt + 1 < nkt) {                                               \
                GEMM_STAGE64(Ap, Bp, Kk, kt + 1, (kt + 1) & 1);               \
                asm volatile("s_waitcnt vmcnt(8)\n\ts_barrier" ::: "memory"); \
            } else {                                                          \
                asm volatile("s_waitcnt vmcnt(0)\n\ts_barrier" ::: "memory"); \
            }                                                                 \
            GEMM_MFMA64(kt & 1);                                              \
            asm volatile("s_waitcnt lgkmcnt(0)\n\ts_barrier" ::: "memory");   \
        }                                                                     \
    }

// ---------------------------------------------------------------------------
// Fused q/k/v projection GEMM: bx 0-7 -> q16, 8-15 -> k16, 16-31 -> vb f32.
// ---------------------------------------------------------------------------
__global__ void __launch_bounds__(256) gemm_qkv(
    const unsigned short* __restrict__ A, const unsigned short* __restrict__ Bt,
    unsigned short* __restrict__ q16, unsigned short* __restrict__ k16,
    float* __restrict__ vb) {
    GEMM_SHARED();
    const int tid = threadIdx.x;
    const int bx = blockIdx.x & 31, by = blockIdx.x >> 5;
    const int m0 = by << 7, n0 = bx << 7;
    const int w = tid >> 6, lane = tid & 63;
    const int wr = (w >> 1) << 6, wc = (w & 1) << 6;
    const int fr = lane & 15, fk8 = (lane >> 4) << 3;
    const int grow = lane >> 2;
    const int gcol = (lane & 3) << 3;

    f32x4 acc[4][4];
#pragma unroll
    for (int i = 0; i < 4; i++)
#pragma unroll
        for (int j = 0; j < 4; j++)
            acc[i][j] = (f32x4){0.f, 0.f, 0.f, 0.f};

    GEMM_KLOOP(A, Bt, Dc);

    const int cr = (lane >> 4) << 2;
    if (bx < 16) {
        unsigned short* Cb = (bx < 8) ? q16 : k16;
        const int coloff = (bx & 7) << 7;
#pragma unroll
        for (int i = 0; i < 4; i++)
#pragma unroll
            for (int j = 0; j < 4; j++) {
#pragma unroll
                for (int r = 0; r < 4; r++) {
                    Cb[(size_t)(m0 + wr + i * 16 + cr + r) * KDIMc + coloff +
                       wc + j * 16 + fr] = f2bf(acc[i][j][r]);
                }
            }
    } else {
        const int coloff = (bx - 16) << 7;
#pragma unroll
        for (int i = 0; i < 4; i++)
#pragma unroll
            for (int j = 0; j < 4; j++) {
#pragma unroll
                for (int r = 0; r < 4; r++) {
                    vb[(size_t)(m0 + wr + i * 16 + cr + r) * VDIMc + coloff +
                       wc + j * 16 + fr] = acc[i][j][r];
                }
            }
    }
}

// ---------------------------------------------------------------------------
// bf16 MFMA GEMM (generic): C f32 = A @ Bt. For output projection.
// ---------------------------------------------------------------------------
__global__ void __launch_bounds__(256) gemm_bf16(
    const unsigned short* __restrict__ A, const unsigned short* __restrict__ Bt,
    float* __restrict__ C, int M, int N, int K) {
    GEMM_SHARED();
    const int tid = threadIdx.x;
    const int nbx = N >> 7;
    const int bx = blockIdx.x % nbx, by = blockIdx.x / nbx;
    const int m0 = by << 7, n0 = bx << 7;
    const int w = tid >> 6, lane = tid & 63;
    const int wr = (w >> 1) << 6, wc = (w & 1) << 6;
    const int fr = lane & 15, fk8 = (lane >> 4) << 3;
    const int grow = lane >> 2;
    const int gcol = (lane & 3) << 3;

    f32x4 acc[4][4];
#pragma unroll
    for (int i = 0; i < 4; i++)
#pragma unroll
        for (int j = 0; j < 4; j++)
            acc[i][j] = (f32x4){0.f, 0.f, 0.f, 0.f};

    GEMM_KLOOP(A, Bt, K);

    const int cr = (lane >> 4) << 2;
#pragma unroll
    for (int i = 0; i < 4; i++)
#pragma unroll
        for (int j = 0; j < 4; j++) {
#pragma unroll
            for (int r = 0; r < 4; r++) {
                C[(size_t)(m0 + wr + i * 16 + cr + r) * N + n0 + wc + j * 16 +
                  fr] = acc[i][j][r];
            }
        }
}

// ---------------------------------------------------------------------------
// Gate GEMM fused with gated RMSNorm epilogue; o read as bf16.
// ---------------------------------------------------------------------------
__global__ void __launch_bounds__(256) gemm_gate_rms(
    const unsigned short* __restrict__ A, const unsigned short* __restrict__ Bt,
    const unsigned short* __restrict__ o, const float* __restrict__ rfac,
    const float* __restrict__ norm_w, unsigned short* __restrict__ out,
    int M, int N, int K) {
    GEMM_SHARED();
    const int tid = threadIdx.x;
    const int nbx = N >> 7;
    const int bx = blockIdx.x % nbx, by = blockIdx.x / nbx;
    const int m0 = by << 7, n0 = bx << 7;
    const int h = n0 >> 7;
    const int w = tid >> 6, lane = tid & 63;
    const int wr = (w >> 1) << 6, wc = (w & 1) << 6;
    const int fr = lane & 15, fk8 = (lane >> 4) << 3;
    const int grow = lane >> 2;
    const int gcol = (lane & 3) << 3;

    f32x4 acc[4][4];
#pragma unroll
    for (int i = 0; i < 4; i++)
#pragma unroll
        for (int j = 0; j < 4; j++)
            acc[i][j] = (f32x4){0.f, 0.f, 0.f, 0.f};

    GEMM_KLOOP(A, Bt, K);

    const int cr = (lane >> 4) << 2;
#pragma unroll
    for (int i = 0; i < 4; i++)
#pragma unroll
        for (int j = 0; j < 4; j++) {
            const int colh = wc + j * 16 + fr;
            const float nw = norm_w[colh];
#pragma unroll
            for (int r = 0; r < 4; r++) {
                const int row = m0 + wr + i * 16 + cr + r;
                float ov = bf2f(o[(size_t)row * VDIMc + n0 + colh]);
                float f = rfac[(size_t)row * Hc + h];
                float y = ov * f * nw * siluf(acc[i][j][r]);
                out[(size_t)row * VDIMc + n0 + colh] = f2bf(y);
            }
        }
}

// ---------------------------------------------------------------------------
// Per-(row,h) RMS factor from bf16 o: rf = rsqrt(mean(o^2)+eps).
// ---------------------------------------------------------------------------
__global__ void __launch_bounds__(256) rfac_kernel(
    const unsigned short* __restrict__ o, float* __restrict__ rf) {
    const int row = blockIdx.x * 4 + (threadIdx.x >> 6);
    const int lane = threadIdx.x & 63;
    const size_t base = (size_t)row * DVc;
    unsigned int pv = *(const unsigned int*)&o[base + lane * 2];
    float o0 = bf2f((unsigned short)(pv & 0xffff));
    float o1 = bf2f((unsigned short)(pv >> 16));
    float ss = o0 * o0 + o1 * o1;
#pragma unroll
    for (int m = 1; m < 64; m <<= 1) ss += __shfl_xor(ss, m, 64);
    if (lane == 0) rf[row] = rsqrtf(ss * (1.f / 128.f) + 1e-5f);
}

// ---------------------------------------------------------------------------
// a/b projections: transposed f32 weights, one wave per 4 rows.
// ---------------------------------------------------------------------------
__global__ void __launch_bounds__(256) ab_proj(
    const float* __restrict__ x, const float* __restrict__ w_aT,
    const float* __restrict__ w_bT, const float* __restrict__ A_log,
    const float* __restrict__ dt_bias, float* __restrict__ g_out,
    float* __restrict__ beta_out) {
    const int wv = threadIdx.x >> 6;
    const int lane = threadIdx.x & 63;
    const int h = lane >> 2, kg = lane & 3;
    const int row0 = blockIdx.x * 16 + wv * 4;
    const float* wa = w_aT + (size_t)h * Dc + kg * 256;
    const float* wb = w_bT + (size_t)h * Dc + kg * 256;
    const float* xr = x + (size_t)row0 * Dc + kg * 256;
    float pa[4] = {0.f, 0.f, 0.f, 0.f}, pb[4] = {0.f, 0.f, 0.f, 0.f};
#pragma unroll 4
    for (int k = 0; k < 256; k += 4) {
        float4 a4 = *(const float4*)&wa[k];
        float4 b4 = *(const float4*)&wb[k];
#pragma unroll
        for (int r = 0; r < 4; r++) {
            float4 x4 = *(const float4*)&xr[(size_t)r * Dc + k];
            pa[r] += dot4(x4, a4);
            pb[r] += dot4(x4, b4);
        }
    }
#pragma unroll
    for (int r = 0; r < 4; r++) {
        pa[r] += __shfl_xor(pa[r], 1, 64);
        pa[r] += __shfl_xor(pa[r], 2, 64);
        pb[r] += __shfl_xor(pb[r], 1, 64);
        pb[r] += __shfl_xor(pb[r], 2, 64);
    }
    if (kg == 0) {
        const float el = __expf(A_log[h]);
        const float db = dt_bias[h];
#pragma unroll
        for (int r = 0; r < 4; r++) {
            float arg = pa[r] + db;
            float sp = fmaxf(arg, 0.f) + log1pf(__expf(-fabsf(arg)));
            g_out[(size_t)(row0 + r) * Hc + h] = -el * sp;
            beta_out[(size_t)(row0 + r) * Hc + h] =
                2.f / (1.f + __expf(-pb[r]));
        }
    }
}

// ---------------------------------------------------------------------------
// Save 3-row halos at 64-step chunk boundaries (for in-place v conv).
// ---------------------------------------------------------------------------
template <int C>
__global__ void __launch_bounds__(256) save_halo(
    const float* __restrict__ in, float* __restrict__ halo) {
    const int g = blockIdx.x * 256 + threadIdx.x;
    const int total = Bc * (Tc / 64 - 1) * 3 * C;
    if (g >= total) return;
    const int c = g % C;
    int r = g / C;
    const int j = r % 3;
    r /= 3;
    const int chunk = r % (Tc / 64 - 1) + 1;
    const int b = r / (Tc / 64 - 1);
    halo[((size_t)(b * 64 + chunk) * 3 + j) * C + c] =
        in[((size_t)b * Tc + chunk * 64 - 3 + j) * C + c];
}

// ---------------------------------------------------------------------------
// Fused q+k depthwise causal conv1d + SiLU + l2norm, bf16->bf16.
// ---------------------------------------------------------------------------
__global__ void __launch_bounds__(256) conv_qk(
    const unsigned short* __restrict__ qin, const float* __restrict__ wq,
    unsigned short* __restrict__ qout, const unsigned short* __restrict__ kin,
    const float* __restrict__ wk, unsigned short* __restrict__ kout) {
    constexpr int C = KDIMc;
    constexpr int CB = C / 256;
    const int half = Bc * (Tc / 64) * CB;
    int bidx = blockIdx.x;
    const unsigned short* in;
    const float* w;
    unsigned short* out;
    if (bidx < half) { in = qin; w = wq; out = qout; }
    else { bidx -= half; in = kin; w = wk; out = kout; }
    const int cb = bidx % CB;
    const int tchunk = (bidx / CB) % (Tc / 64);
    const int b = bidx / (CB * (Tc / 64));
    const int c = cb * 256 + threadIdx.x;
    const int t0 = tchunk * 64;
    const float w0 = w[c * 4 + 0], w1 = w[c * 4 + 1], w2 = w[c * 4 + 2],
                w3 = w[c * 4 + 3];
    const unsigned short* src = in + (size_t)b * Tc * C + c;
    float xm3 = (t0 >= 3) ? bf2f(src[(size_t)(t0 - 3) * C]) : 0.f;
    float xm2 = (t0 >= 2) ? bf2f(src[(size_t)(t0 - 2) * C]) : 0.f;
    float xm1 = (t0 >= 1) ? bf2f(src[(size_t)(t0 - 1) * C]) : 0.f;
    unsigned short* dst = out + (size_t)b * Tc * C + c;
#pragma unroll 4
    for (int i = 0; i < 64; i++) {
        float xt = bf2f(src[(size_t)(t0 + i) * C]);
        float y = w0 * xm3 + w1 * xm2 + w2 * xm1 + w3 * xt;
        y = siluf(y);
        {
            float ss = y * y;
#pragma unroll
            for (int m = 1; m < 64; m <<= 1) ss += __shfl_xor(ss, m, 64);
            y *= rsqrtf(ss + 1e-6f);
        }
        dst[(size_t)(t0 + i) * C] = f2bf(y);
        xm3 = xm2;
        xm2 = xm1;
        xm1 = xt;
    }
}

// ---------------------------------------------------------------------------
// Depthwise causal conv1d (K=4) + SiLU, IN PLACE f32 (for v).
// ---------------------------------------------------------------------------
template <int C, bool L2N>
__global__ void __launch_bounds__(256) conv_silu_inplace(
    float* __restrict__ buf, const float* __restrict__ w,
    const float* __restrict__ halo) {
    constexpr int CB = C / 256;
    const int bidx = blockIdx.x;
    const int cb = bidx % CB;
    const int tchunk = (bidx / CB) % (Tc / 64);
    const int b = bidx / (CB * (Tc / 64));
    const int c = cb * 256 + threadIdx.x;
    const int t0 = tchunk * 64;
    const float w0 = w[c * 4 + 0], w1 = w[c * 4 + 1], w2 = w[c * 4 + 2],
                w3 = w[c * 4 + 3];
    float xm3 = 0.f, xm2 = 0.f, xm1 = 0.f;
    if (tchunk > 0) {
        const float* hp = halo + (size_t)(b * 64 + tchunk) * 3 * C + c;
        xm3 = hp[0];
        xm2 = hp[C];
        xm1 = hp[2 * C];
    }
    float* p = buf + (size_t)b * Tc * C + c;
#pragma unroll 4
    for (int i = 0; i < 64; i++) {
        float xt = p[(size_t)(t0 + i) * C];
        float y = w0 * xm3 + w1 * xm2 + w2 * xm1 + w3 * xt;
        y = siluf(y);
        if (L2N) {
            float ss = y * y;
#pragma unroll
            for (int m = 1; m < 64; m <<= 1) ss += __shfl_xor(ss, m, 64);
            y *= rsqrtf(ss + 1e-6f);
        }
        p[(size_t)(t0 + i) * C] = y;
        xm3 = xm2;
        xm2 = xm1;
        xm1 = xt;
    }
}

// ---------------------------------------------------------------------------
// TM precompute: Gram via bf16 MFMA, f32 solve (readlane broadcast).
// T,M stored bf16 [t][s].
// ---------------------------------------------------------------------------
__global__ void __launch_bounds__(256) tm_precompute(
    const unsigned short* __restrict__ kc, const unsigned short* __restrict__ qc,
    const float* __restrict__ g, const float* __restrict__ beta,
    unsigned short* __restrict__ tmT, unsigned short* __restrict__ tmM) {
    const int bid = blockIdx.x;
    const int ch = bid & (NCH - 1);
    const int bh = bid >> 6;
    const int b = bh >> 4, h = bh & 15;
    const int tid = threadIdx.x;
    const int t0 = ch * CC;

    __shared__ __align__(16) unsigned short kb16[CC][72];
    __shared__ __align__(16) unsigned short qb16[CC][72];
    __shared__ __align__(16) float AtL[CC][DKc + 4];  // A^T: AtL[s][t]
    __shared__ float cL[CC], betaL[CC];

    const size_t qk0 = (size_t)b * Tc * KDIMc + h * DKc;
    const size_t gb0 = (size_t)b * Tc * Hc + h;
    const size_t tile = (size_t)(bh * NCH + ch) * 4096;

#pragma unroll
    for (int i = 0; i < 2; i++) {
        int e = tid + i * 256;
        int r = e >> 3, c8 = (e & 7) << 3;
        *(short8*)&kb16[r][c8] =
            *(const short8*)&kc[qk0 + (size_t)(t0 + r) * KDIMc + c8];
        *(short8*)&qb16[r][c8] =
            *(const short8*)&qc[qk0 + (size_t)(t0 + r) * KDIMc + c8];
    }
    if (tid < 64) {
        float gv = g[gb0 + (size_t)(t0 + tid) * Hc];
        float cv = gv;
#pragma unroll
        for (int d = 1; d < 64; d <<= 1) {
            float nb = __shfl_up(cv, d, 64);
            if (tid >= d) cv += nb;
        }
        cL[tid] = cv;
        betaL[tid] = beta[gb0 + (size_t)(t0 + tid) * Hc];
    }
    __syncthreads();

    {
        const int w = tid >> 6, lane = tid & 63;
        const int fr = lane & 15, fk8 = (lane >> 4) << 3;
        const int rr = (lane >> 4) << 2;
        short8 ak0 = *(const short8*)&kb16[w * 16 + fr][fk8];
        short8 ak1 = *(const short8*)&kb16[w * 16 + fr][fk8 + 32];
        short8 aq0 = *(const short8*)&qb16[w * 16 + fr][fk8];
        short8 aq1 = *(const short8*)&qb16[w * 16 + fr][fk8 + 32];
#pragma unroll
        for (int j = 0; j < 4; j++) {
            short8 b0 = *(const short8*)&kb16[j * 16 + fr][fk8];
            short8 b1 = *(const short8*)&kb16[j * 16 + fr][fk8 + 32];
            f32x4 kk = (f32x4){0.f, 0.f, 0.f, 0.f};
            f32x4 qk = (f32x4){0.f, 0.f, 0.f, 0.f};
            kk = __builtin_amdgcn_mfma_f32_16x16x32_bf16(ak0, b0, kk, 0, 0, 0);
            kk = __builtin_amdgcn_mfma_f32_16x16x32_bf16(ak1, b1, kk, 0, 0, 0);
            qk = __builtin_amdgcn_mfma_f32_16x16x32_bf16(aq0, b0, qk, 0, 0, 0);
            qk = __builtin_amdgcn_mfma_f32_16x16x32_bf16(aq1, b1, qk, 0, 0, 0);
#pragma unroll
            for (int r = 0; r < 4; r++) {
                int t = w * 16 + rr + r, s = j * 16 + fr;
                float E = (s <= t) ? __expf(cL[t] - cL[s]) : 0.f;
                AtL[s][t] = (s < t) ? betaL[t] * E * kk[r] : 0.f;
                tmM[tile + (size_t)t * 64 + s] =
                    (s <= t) ? f2bf(0.125f * E * qk[r]) : (unsigned short)0;
            }
        }
    }
    __syncthreads();

    {
        const int w = tid >> 6, lane = tid & 63;
        float acc[16];
#pragma unroll
        for (int di = 0; di < 16; di++)
            acc[di] = (lane == w * 16 + di) ? 1.f : 0.f;
        // Forward substitution, fully unrolled; readlane broadcast (SALU).
#pragma unroll
        for (int s = 0; s < 64; s++) {
            float a = AtL[s][lane];
            float ds[16];
#pragma unroll
            for (int di = 0; di < 16; di++)
                ds[di] = __uint_as_float(
                    __builtin_amdgcn_readlane(__float_as_uint(acc[di]), s));
#pragma unroll
            for (int di = 0; di < 16; di++)
                acc[di] = fmaf(-a, ds[di], acc[di]);
        }
        unsigned short tb[16];
#pragma unroll
        for (int di = 0; di < 16; di++) tb[di] = f2bf(acc[di]);
        *(uint4*)&tmT[tile + (size_t)lane * 64 + w * 16] = *(uint4*)&tb[0];
        *(uint4*)&tmT[tile + (size_t)lane * 64 + w * 16 + 8] = *(uint4*)&tb[8];
    }
}

// ---------------------------------------------------------------------------
// Sequential chunk scan (R19-proven): conflict-free K^T staging, all-MFMA
// phases, register-resident S, V read f32, O stored bf16. 8-way DV split.
// ---------------------------------------------------------------------------
__global__ void __launch_bounds__(512, 2) delta_scan(
    const unsigned short* __restrict__ kc, const unsigned short* __restrict__ qc,
    const unsigned short* __restrict__ kcT,  // [B][KDIM][T]
    const float* __restrict__ vc, unsigned short* __restrict__ o16,
    const float* __restrict__ g, const float* __restrict__ beta,
    const unsigned short* __restrict__ tmT,
    const unsigned short* __restrict__ tmM) {
    const int bid = blockIdx.x;
    const int sl = bid >> 5;   // 0..7
    const int bh = bid & 31;   // 0..31 -> XCD = bh%8
    const int b = bh >> 4, h = bh & 15;
    const int tid = threadIdx.x;

    __shared__ __align__(16) float VL[CC][20];
    __shared__ float gamL[CC], egL[CC], betaL[CC];
    __shared__ __align__(16) unsigned short kb16[CC][72];  // K rows
    __shared__ __align__(16) unsigned short kh16[CC][72];  // K^T: [dk][t]
    __shared__ __align__(16) unsigned short qb16[CC][72];
    __shared__ __align__(16) unsigned short Tb16[CC][72];
    __shared__ __align__(16) unsigned short Mb16[CC][72];
    __shared__ __align__(16) unsigned short STb16[16][72];  // S^T bf16 copy
    __shared__ __align__(16) unsigned short DTb16[16][72];  // RHS^T bf16
    __shared__ __align__(16) unsigned short D2b16[16][72];  // delta^T bf16
    __shared__ __align__(16) unsigned short egd16[16][72];  // (eg*delta)^T

    const size_t qk0 = (size_t)b * Tc * KDIMc + h * DKc;
    const size_t kT0 = ((size_t)b * KDIMc + h * DKc) * Tc;
    const size_t v0 = (size_t)b * Tc * VDIMc + h * DVc + sl * 16;
    const size_t gb0 = (size_t)b * Tc * Hc + h;
    const size_t tb0 = (size_t)(bh * NCH) * 4096;

    for (int i = tid; i < 16 * 72; i += 512) ((unsigned short*)STb16)[i] = 0;

    const int r8 = tid >> 3, c8 = (tid & 7) << 3;  // bf16 staging coords
    const int wid = tid >> 6, lane = tid & 63;
    const int fr = lane & 15;
    const int fk8 = (lane >> 4) << 3;
    const int rr = (lane >> 4) << 2;

    f32x4 accS = (f32x4){0.f, 0.f, 0.f, 0.f};  // waves 0-3: S[w*16+rr+r][fr]

    short8 kv, kvT, qv, tv, mv;
    float4 vv0;
    float gvr = 0.f, bvr = 0.f;

#define LOADREGS(CH)                                                          \
    {                                                                         \
        const size_t tK = qk0 + (size_t)(CH) * CC * KDIMc;                    \
        const size_t tile_ = tb0 + (size_t)(CH) * 4096;                       \
        kv = *(const short8*)&kc[tK + (size_t)r8 * KDIMc + c8];               \
        kvT = *(const short8*)&kcT[kT0 + (size_t)r8 * Tc + (CH) * CC + c8];   \
        qv = *(const short8*)&qc[tK + (size_t)r8 * KDIMc + c8];               \
        tv = *(const short8*)&tmT[tile_ + (size_t)tid * 8];                   \
        mv = *(const short8*)&tmM[tile_ + (size_t)tid * 8];                   \
        if (tid < 256)                                                        \
            vv0 = *(const float4*)&vc[v0 +                                    \
                                      (size_t)((CH) * CC + (tid >> 2)) *     \
                                          VDIMc +                             \
                                      ((tid & 3) << 2)];                      \
        if (tid < 64) {                                                       \
            gvr = g[gb0 + (size_t)((CH) * CC + tid) * Hc];                    \
            bvr = beta[gb0 + (size_t)((CH) * CC + tid) * Hc];                 \
        }                                                                     \
    }

    LOADREGS(0);

#pragma unroll 1
    for (int ch = 0; ch < NCH; ch++) {
        __syncthreads();  // B0: prev chunk fully done (STb16 visible)

        // ---- stage regs -> LDS (pure short8 copies; no conversions)
        {
            *(short8*)&kb16[r8][c8] = kv;
            *(short8*)&kh16[r8][c8] = kvT;
            *(short8*)&qb16[r8][c8] = qv;
            *(short8*)&Tb16[r8][c8] = tv;
            *(short8*)&Mb16[r8][c8] = mv;
            if (tid < 256) *(float4*)&VL[tid >> 2][(tid & 3) << 2] = vv0;
            if (tid < 64) {
                float cv = gvr;
#pragma unroll
                for (int d = 1; d < 64; d <<= 1) {
                    float nb = __shfl_up(cv, d, 64);
                    if (tid >= d) cv += nb;
                }
                gamL[tid] = __expf(cv);
                float cend = __shfl(cv, 63, 64);
                egL[tid] = __expf(cend - cv);
                betaL[tid] = bvr;
            }
        }
        if (ch + 1 < NCH) LOADREGS(ch + 1);
        __syncthreads();  // B1: stage visible

        // ---- phase 1: KS (waves 0-3) and QS (waves 4-7) via MFMA
        f32x4 acc1 = (f32x4){0.f, 0.f, 0.f, 0.f};
        {
            short8 bs0 = *(const short8*)&STb16[fr][fk8];
            short8 bs1 = *(const short8*)&STb16[fr][fk8 + 32];
            if (wid < 4) {
                const int m0 = wid << 4;
                short8 a0 = *(const short8*)&kb16[m0 + fr][fk8];
                short8 a1 = *(const short8*)&kb16[m0 + fr][fk8 + 32];
                acc1 = __builtin_amdgcn_mfma_f32_16x16x32_bf16(a0, bs0, acc1, 0, 0, 0);
                acc1 = __builtin_amdgcn_mfma_f32_16x16x32_bf16(a1, bs1, acc1, 0, 0, 0);
#pragma unroll
                for (int r = 0; r < 4; r++) {
                    int t = m0 + rr + r;
                    float rhs = betaL[t] * (VL[t][fr] - gamL[t] * acc1[r]);
                    DTb16[fr][t] = f2bf(rhs);
                }
            } else {
                const int m0 = (wid - 4) << 4;
                short8 a0 = *(const short8*)&qb16[m0 + fr][fk8];
                short8 a1 = *(const short8*)&qb16[m0 + fr][fk8 + 32];
                acc1 = __builtin_amdgcn_mfma_f32_16x16x32_bf16(a0, bs0, acc1, 0, 0, 0);
                acc1 = __builtin_amdgcn_mfma_f32_16x16x32_bf16(a1, bs1, acc1, 0, 0, 0);
#pragma unroll
                for (int r = 0; r < 4; r++) {
                    int t = m0 + rr + r;
                    acc1[r] *= 0.125f * gamL[t];
                }
            }
        }
        __syncthreads();  // B2: RHS ready

        // ---- phase 2: delta = T * RHS (waves 0-3); write delta and eg*delta
        if (wid < 4) {
            const int m0 = wid << 4;
            short8 a0 = *(const short8*)&Tb16[m0 + fr][fk8];
            short8 a1 = *(const short8*)&Tb16[m0 + fr][fk8 + 32];
            short8 b0 = *(const short8*)&DTb16[fr][fk8];
            short8 b1 = *(const short8*)&DTb16[fr][fk8 + 32];
            f32x4 d = (f32x4){0.f, 0.f, 0.f, 0.f};
            d = __builtin_amdgcn_mfma_f32_16x16x32_bf16(a0, b0, d, 0, 0, 0);
            d = __builtin_amdgcn_mfma_f32_16x16x32_bf16(a1, b1, d, 0, 0, 0);
#pragma unroll
            for (int r = 0; r < 4; r++) {
                int t = m0 + rr + r;
                D2b16[fr][t] = f2bf(d[r]);
                egd16[fr][t] = f2bf(egL[t] * d[r]);
            }
        }
        __syncthreads();  // B3: delta ready

        // ---- phase 3 (waves 4-7): O = M*delta + scaledQS, store bf16.
        //      phase 4 (waves 0-3): S = ge*S + K^T(eg*delta) via MFMA.
        if (wid >= 4) {
            const int m0 = (wid - 4) << 4;
            short8 a0 = *(const short8*)&Mb16[m0 + fr][fk8];
            short8 a1 = *(const short8*)&Mb16[m0 + fr][fk8 + 32];
            short8 b0 = *(const short8*)&D2b16[fr][fk8];
            short8 b1 = *(const short8*)&D2b16[fr][fk8 + 32];
            f32x4 o = acc1;  // 0.125*gam*QS
            o = __builtin_amdgcn_mfma_f32_16x16x32_bf16(a0, b0, o, 0, 0, 0);
            o = __builtin_amdgcn_mfma_f32_16x16x32_bf16(a1, b1, o, 0, 0, 0);
#pragma unroll
            for (int r = 0; r < 4; r++)
                o16[v0 + (size_t)(ch * CC + m0 + rr + r) * VDIMc + fr] =
                    f2bf(o[r]);
        } else {
            const int m0 = wid << 4;
            const float ge = gamL[63];
            short8 a0 = *(const short8*)&kh16[m0 + fr][fk8];
            short8 a1 = *(const short8*)&kh16[m0 + fr][fk8 + 32];
            short8 b0 = *(const short8*)&egd16[fr][fk8];
            short8 b1 = *(const short8*)&egd16[fr][fk8 + 32];
#pragma unroll
            for (int r = 0; r < 4; r++) accS[r] *= ge;
            accS = __builtin_amdgcn_mfma_f32_16x16x32_bf16(a0, b0, accS, 0, 0, 0);
            accS = __builtin_amdgcn_mfma_f32_16x16x32_bf16(a1, b1, accS, 0, 0, 0);
#pragma unroll
            for (int r = 0; r < 4; r++)
                STb16[fr][m0 + rr + r] = f2bf(accS[r]);
        }
    }
#undef LOADREGS
}

// ---------------------------------------------------------------------------
// Workspace (floats), 236 MB (R18/R19-proven layout):
//   qb 8.39M (q16raw -> kcT16) | kb 8.39M (k16raw -> o16) | vb 16.78M f32 |
//   tm-region 16.78M (tmT16|tmM16|qc16|kc16 shorts; halo aliases start) |
//   gbuf | bbuf | xtra.  obb aliases tm start (after scan); rfac = gbuf.
// ---------------------------------------------------------------------------
extern "C" void kernel_launch(void* const* d_in, const int* in_sizes, int n_in,
                              void* d_out, int out_size, void* d_ws,
                              size_t ws_size, hipStream_t stream) {
    const float* x = (const float*)d_in[0];
    const float* w_q = (const float*)d_in[1];
    const float* w_k = (const float*)d_in[2];
    const float* w_v = (const float*)d_in[3];
    const float* w_a = (const float*)d_in[4];
    const float* w_b = (const float*)d_in[5];
    const float* w_g = (const float*)d_in[6];
    const float* w_out = (const float*)d_in[7];
    const float* A_log = (const float*)d_in[8];
    const float* dt_bias = (const float*)d_in[9];
    const float* conv_q = (const float*)d_in[10];
    const float* conv_k = (const float*)d_in[11];
    const float* conv_v = (const float*)d_in[12];
    const float* norm_w = (const float*)d_in[13];

    float* ws = (float*)d_ws;
    const size_t M = Mrows;
    float* qb = ws;
    float* kb = qb + M * KDIMc;
    float* vb = kb + M * KDIMc;
    float* tm = vb + M * VDIMc;          // 16.78M floats region
    float* gbuf = tm + M * VDIMc;
    float* bbuf = gbuf + M * Hc;
    float* xtra = bbuf + M * Hc;

    unsigned short* q16raw = (unsigned short*)qb;
    unsigned short* k16raw = (unsigned short*)kb;
    unsigned short* kcT16 = (unsigned short*)qb;  // alias: after conv_q
    unsigned short* o16 = (unsigned short*)kb;    // alias: after conv_k
    unsigned short* tmS = (unsigned short*)tm;
    unsigned short* tmT16 = tmS;
    unsigned short* tmM16 = tmS + (size_t)8388608;
    unsigned short* qc16 = tmS + (size_t)16777216;
    unsigned short* kc16 = tmS + (size_t)25165824;
    float* halo = tm;                     // dead before tm_precompute
    unsigned short* obb = tmS;            // after scan, tmT/tmM dead
    float* rfac = gbuf;                   // g dead after scan

    unsigned short* xb = (unsigned short*)xtra;
    unsigned short* wqT = xb + M * KDIMc;
    unsigned short* wkT = wqT + (size_t)KDIMc * Dc;
    unsigned short* wvT = wkT + (size_t)KDIMc * Dc;  // wqT|wkT|wvT contiguous
    unsigned short* wgT = wvT + (size_t)VDIMc * Dc;
    unsigned short* woT = wgT + (size_t)VDIMc * Dc;
    float* waT = (float*)(woT + (size_t)Dc * VDIMc);
    float* wbT = waT + (size_t)16 * Dc;

    // 0) fused prep: weight transposes + a/b transposes + x convert
    prep_all<<<dim3(1024 + 1024 + 2048 + 2048 + 2048 + 16 + 16 + 8192), 256,
               0, stream>>>(x, w_q, w_k, w_v, w_g, w_out, w_a, w_b, xb, wqT,
                            wkT, wvT, wgT, woT, waT, wbT);

    // 1) fused q/k/v projection (one GEMM, BK=64; q/k out bf16, v f32)
    gemm_qkv<<<dim3((M / 128) * 32), 256, 0, stream>>>(xb, wqT, q16raw, k16raw,
                                                       vb);

    // 2) a/b projections -> g, beta
    ab_proj<<<dim3(M / 16), 256, 0, stream>>>(x, waT, wbT, A_log, dt_bias,
                                              gbuf, bbuf);

    // 3) conv + silu: fused q+k bf16->bf16 (+l2norm); v in-place f32
    conv_qk<<<dim3(2 * Bc * (Tc / 64) * (KDIMc / 256)), 256, 0, stream>>>(
        q16raw, conv_q, qc16, k16raw, conv_k, kc16);
    // kcT16 = kc16 transposed to [B][KDIM][T] (aliases qb; conv_q done)
    transp_k16<<<dim3(Bc * 16 * 64), 256, 0, stream>>>(kc16, kcT16);
    {
        const int nv = Bc * (Tc / 64 - 1) * 3 * VDIMc;
        save_halo<VDIMc><<<dim3((nv + 255) / 256), 256, 0, stream>>>(vb, halo);
        conv_silu_inplace<VDIMc, false>
            <<<dim3(Bc * (Tc / 64) * (VDIMc / 256)), 256, 0, stream>>>(
                vb, conv_v, halo);
    }

    // 4a) parallel precompute of T=(I+A)^{-1} and M (bf16 out)
    tm_precompute<<<dim3(Bc * Hc * NCH), 256, 0, stream>>>(
        kc16, qc16, gbuf, bbuf, tmT16, tmM16);
    // 4b) sequential scan (8-way DV split, R19-proven)
    delta_scan<<<dim3(Bc * Hc * 8), 512, 0, stream>>>(
        kc16, qc16, kcT16, vb, o16, gbuf, bbuf, tmT16, tmM16);

    // 5) rms factors from bf16 o, then gate GEMM fused with rms epilogue
    rfac_kernel<<<dim3(M * Hc / 4), 256, 0, stream>>>(o16, rfac);
    gemm_gate_rms<<<dim3((M / 128) * (VDIMc / 128)), 256, 0, stream>>>(
        xb, wgT, o16, rfac, norm_w, obb, M, VDIMc, Dc);

    // 6) output projection (bf16 MFMA, BK=64) -> d_out
    gemm_bf16<<<dim3((M / 128) * (Dc / 128)), 256, 0, stream>>>(
        obb, woT, (float*)d_out, M, Dc, VDIMc);
}

// Round 28
// 484.461 us; speedup vs baseline: 1.0823x; 1.0042x over previous
//
#include <hip/hip_runtime.h>
#include <hip/hip_bf16.h>
#include <math.h>

// Problem constants
#define Bc 2
#define Tc 4096
#define Dc 1024
#define Hc 16
#define DKc 64
#define DVc 128
#define KDIMc 1024   // H*DK
#define VDIMc 2048   // H*DV
#define Mrows (Bc*Tc) // 8192
#define CC 64        // scan chunk size
#define NCH (Tc/CC)  // 64 chunks

typedef short short8 __attribute__((ext_vector_type(8)));
typedef float f32x4 __attribute__((ext_vector_type(4)));

__device__ __forceinline__ float siluf(float x) {
    return x / (1.f + __expf(-x));
}
__device__ __forceinline__ float dot4(float4 a, float4 b) {
    return a.x * b.x + a.y * b.y + a.z * b.z + a.w * b.w;
}
__device__ __forceinline__ unsigned short f2bf(float f) {
    unsigned int u = __float_as_uint(f);
    unsigned int r = (u + 0x7fffu + ((u >> 16) & 1u)) >> 16;
    return (unsigned short)r;
}
__device__ __forceinline__ unsigned int pk2(float a, float b) {
    return (unsigned)f2bf(a) | ((unsigned)f2bf(b) << 16);
}
__device__ __forceinline__ float bf2f(unsigned short s) {
    unsigned int u = ((unsigned int)s) << 16;
    return __uint_as_float(u);
}
// async global->LDS DMA, 16B per lane; lds base must be wave-uniform.
__device__ __forceinline__ void gload16(const unsigned short* g,
                                        unsigned short* l) {
    __builtin_amdgcn_global_load_lds(
        (const __attribute__((address_space(1))) unsigned int*)g,
        (__attribute__((address_space(3))) unsigned int*)l, 16, 0, 0);
}

// ---------------------------------------------------------------------------
// Fused prep kernel: 5 bf16 weight transposes + 2 f32 a/b transposes +
// x f32->bf16 convert, dispatched by blockIdx range (provably disjoint).
// ---------------------------------------------------------------------------
__device__ void tile_transp_bf16(const float* __restrict__ in,
                                 unsigned short* __restrict__ out, int K,
                                 int N, int blk) {
    __shared__ float t[32][33];
    const int nbx = N >> 5;
    const int n0 = (blk % nbx) << 5;
    const int k0 = (blk / nbx) << 5;
    const int c = threadIdx.x & 31, r4 = (threadIdx.x >> 5) << 2;
#pragma unroll
    for (int i = 0; i < 4; i++)
        t[r4 + i][c] = in[(size_t)(k0 + r4 + i) * N + n0 + c];
    __syncthreads();
#pragma unroll
    for (int i = 0; i < 4; i++)
        out[(size_t)(n0 + r4 + i) * K + k0 + c] = f2bf(t[c][r4 + i]);
}

__device__ void tile_transp_f32w(const float* __restrict__ in,
                                 float* __restrict__ out, int blk) {
    __shared__ float t2[64][17];
    const int k0 = blk * 64;
    const int r = threadIdx.x >> 2, c4 = (threadIdx.x & 3) << 2;
    float4 v = *(const float4*)&in[(size_t)(k0 + r) * 16 + c4];
    t2[r][c4 + 0] = v.x;
    t2[r][c4 + 1] = v.y;
    t2[r][c4 + 2] = v.z;
    t2[r][c4 + 3] = v.w;
    __syncthreads();
    const int n = threadIdx.x >> 4;
    const int kk = (threadIdx.x & 15) << 2;
    out[(size_t)n * Dc + k0 + kk + 0] = t2[kk + 0][n];
    out[(size_t)n * Dc + k0 + kk + 1] = t2[kk + 1][n];
    out[(size_t)n * Dc + k0 + kk + 2] = t2[kk + 2][n];
    out[(size_t)n * Dc + k0 + kk + 3] = t2[kk + 3][n];
}

__global__ void __launch_bounds__(256) prep_all(
    const float* __restrict__ x, const float* __restrict__ w_q,
    const float* __restrict__ w_k, const float* __restrict__ w_v,
    const float* __restrict__ w_g, const float* __restrict__ w_out,
    const float* __restrict__ w_a, const float* __restrict__ w_b,
    unsigned short* __restrict__ xb, unsigned short* __restrict__ wqT,
    unsigned short* __restrict__ wkT, unsigned short* __restrict__ wvT,
    unsigned short* __restrict__ wgT, unsigned short* __restrict__ woT,
    float* __restrict__ waT, float* __restrict__ wbT) {
    int blk = blockIdx.x;
    if (blk < 1024) { tile_transp_bf16(w_q, wqT, Dc, KDIMc, blk); return; }
    blk -= 1024;
    if (blk < 1024) { tile_transp_bf16(w_k, wkT, Dc, KDIMc, blk); return; }
    blk -= 1024;
    if (blk < 2048) { tile_transp_bf16(w_v, wvT, Dc, VDIMc, blk); return; }
    blk -= 2048;
    if (blk < 2048) { tile_transp_bf16(w_g, wgT, Dc, VDIMc, blk); return; }
    blk -= 2048;
    if (blk < 2048) { tile_transp_bf16(w_out, woT, VDIMc, Dc, blk); return; }
    blk -= 2048;
    if (blk < 16) { tile_transp_f32w(w_a, waT, blk); return; }
    blk -= 16;
    if (blk < 16) { tile_transp_f32w(w_b, wbT, blk); return; }
    blk -= 16;
    // x convert: 8192 blocks, 4 floats/thread
    int g = blk * 256 + threadIdx.x;
    float4 v = *(const float4*)&x[(size_t)g * 4];
    *(uint2*)&xb[(size_t)g * 4] = make_uint2(pk2(v.x, v.y), pk2(v.z, v.w));
}

// ---------------------------------------------------------------------------
// bf16 tile transpose: in [B][T][KDIM] -> out [B][KDIM][T]. 64x64 tiles.
// ---------------------------------------------------------------------------
__global__ void __launch_bounds__(256) transp_k16(
    const unsigned short* __restrict__ in, unsigned short* __restrict__ out) {
    __shared__ unsigned short t[64][68];  // 136B rows (8B-aligned)
    const int bx = blockIdx.x & 63;          // t-block
    const int by = (blockIdx.x >> 6) & 15;   // c-block (KDIM/64)
    const int b = blockIdx.x >> 10;
    const int t0 = bx << 6, c0 = by << 6;
    {
        const int row = threadIdx.x >> 2, c16 = (threadIdx.x & 3) << 4;
        const unsigned short* src =
            &in[((size_t)b * Tc + t0 + row) * KDIMc + c0 + c16];
#pragma unroll
        for (int i = 0; i < 4; i++)
            *(uint2*)&t[row][c16 + i * 4] = *(const uint2*)&src[i * 4];
    }
    __syncthreads();
    {
        const int cc = threadIdx.x & 63, tp = (threadIdx.x >> 6) << 4;
        unsigned short v[16];
#pragma unroll
        for (int i = 0; i < 16; i++) v[i] = t[tp + i][cc];
        unsigned short* dst =
            &out[((size_t)b * KDIMc + c0 + cc) * Tc + t0 + tp];
        *(uint4*)&dst[0] = *(uint4*)&v[0];
        *(uint4*)&dst[8] = *(uint4*)&v[8];
    }
}

// ---------------------------------------------------------------------------
// GEMM building blocks, BK=64, counted-vmcnt double-buffered pipeline (T4,
// R27-proven): prefetch next tile into buf^1, fused {s_waitcnt vmcnt(8);
// s_barrier} keeps the 8 prefetch loads in flight across the barrier, then
// MFMA current buf, then {lgkmcnt(0); s_barrier}. Race-free (see R27).
// R28 adds XCD-aware bijective block swizzle (T1): blocks sharing an
// A-panel land on the same XCD's L2 -> staging loads become L2-hits,
// shrinking the latency the vmcnt(8) wait exposes.
// ---------------------------------------------------------------------------
#define GEMM_SHARED()                                                         \
    __shared__ unsigned short As0[2][128 * 32], As1[2][128 * 32];             \
    __shared__ unsigned short Bs0[2][128 * 32], Bs1[2][128 * 32];

// bijective when gridDim.x % 8 == 0 (2048 / 1024 / 512 here)
#define XCD_SWZ()                                                             \
    const int bid = ((int)blockIdx.x & 7) * ((int)gridDim.x >> 3) +           \
                    ((int)blockIdx.x >> 3);

#define GEMM_STAGE64(Ap, Bp, Kk, KT, PB)                                      \
    {                                                                         \
        const size_t kb0 = (size_t)((KT) << 6) + gcol;                        \
        const size_t kb1 = kb0 + 32;                                          \
        _Pragma("unroll") for (int r = 0; r < 2; r++) {                       \
            const int rows = r * 64 + w * 16;                                 \
            gload16(&Ap[(size_t)(m0 + rows + grow) * Kk + kb0],               \
                    &As0[PB][rows * 32]);                                     \
            gload16(&Ap[(size_t)(m0 + rows + grow) * Kk + kb1],               \
                    &As1[PB][rows * 32]);                                     \
            gload16(&Bp[(size_t)(n0 + rows + grow) * Kk + kb0],               \
                    &Bs0[PB][rows * 32]);                                     \
            gload16(&Bp[(size_t)(n0 + rows + grow) * Kk + kb1],               \
                    &Bs1[PB][rows * 32]);                                     \
        }                                                                     \
    }

#define GEMM_MFMA64(PB)                                                       \
    {                                                                         \
        short8 af[4], bfr[4];                                                 \
        _Pragma("unroll") for (int i = 0; i < 4; i++)                         \
            af[i] = *(const short8*)&As0[PB][(wr + i * 16 + fr) * 32 + fk8];  \
        _Pragma("unroll") for (int j = 0; j < 4; j++)                         \
            bfr[j] = *(const short8*)&Bs0[PB][(wc + j * 16 + fr) * 32 + fk8]; \
        _Pragma("unroll") for (int i = 0; i < 4; i++)                         \
            _Pragma("unroll") for (int j = 0; j < 4; j++)                     \
                acc[i][j] = __builtin_amdgcn_mfma_f32_16x16x32_bf16(          \
                    af[i], bfr[j], acc[i][j], 0, 0, 0);                       \
        _Pragma("unroll") for (int i = 0; i < 4; i++)                         \
            af[i] = *(const short8*)&As1[PB][(wr + i * 16 + fr) * 32 + fk8];  \
        _Pragma("unroll") for (int j = 0; j < 4; j++)                         \
            bfr[j] = *(const short8*)&Bs1[PB][(wc + j * 16 + fr) * 32 + fk8]; \
        _Pragma("unroll") for (int i = 0; i < 4; i++)                         \
            _Pragma("unroll") for (int j = 0; j < 4; j++)                     \
                acc[i][j] = __builtin_amdgcn_mfma_f32_16x16x32_bf16(          \
                    af[i], bfr[j], acc[i][j], 0, 0, 0);                       \
    }

#define GEMM_KLOOP(Ap, Bp, Kk)                                                \
    {                                                                         \
        const int nkt = (Kk) >> 6;                                            \
        GEMM_STAGE64(Ap, Bp, Kk, 0, 0);                                       \
        for (int kt = 0; kt < nkt; kt++) {                                    \
            if (kt + 1 < nkt) {                                               \
                GEMM_STAGE64(Ap, Bp, Kk, kt + 1, (kt + 1) & 1);               \
                asm volatile("s_waitcnt vmcnt(8)\n\ts_barrier" ::: "memory"); \
            } else {                                                          \
                asm volatile("s_waitcnt vmcnt(0)\n\ts_barrier" ::: "memory"); \
            }                                                                 \
            GEMM_MFMA64(kt & 1);                                              \
            asm volatile("s_waitcnt lgkmcnt(0)\n\ts_barrier" ::: "memory");   \
        }                                                                     \
    }

// ---------------------------------------------------------------------------
// Fused q/k/v projection GEMM: bx 0-7 -> q16, 8-15 -> k16, 16-31 -> vb f32.
// ---------------------------------------------------------------------------
__global__ void __launch_bounds__(256) gemm_qkv(
    const unsigned short* __restrict__ A, const unsigned short* __restrict__ Bt,
    unsigned short* __restrict__ q16, unsigned short* __restrict__ k16,
    float* __restrict__ vb) {
    GEMM_SHARED();
    XCD_SWZ();
    const int tid = threadIdx.x;
    const int bx = bid & 31, by = bid >> 5;
    const int m0 = by << 7, n0 = bx << 7;
    const int w = tid >> 6, lane = tid & 63;
    const int wr = (w >> 1) << 6, wc = (w & 1) << 6;
    const int fr = lane & 15, fk8 = (lane >> 4) << 3;
    const int grow = lane >> 2;
    const int gcol = (lane & 3) << 3;

    f32x4 acc[4][4];
#pragma unroll
    for (int i = 0; i < 4; i++)
#pragma unroll
        for (int j = 0; j < 4; j++)
            acc[i][j] = (f32x4){0.f, 0.f, 0.f, 0.f};

    GEMM_KLOOP(A, Bt, Dc);

    const int cr = (lane >> 4) << 2;
    if (bx < 16) {
        unsigned short* Cb = (bx < 8) ? q16 : k16;
        const int coloff = (bx & 7) << 7;
#pragma unroll
        for (int i = 0; i < 4; i++)
#pragma unroll
            for (int j = 0; j < 4; j++) {
#pragma unroll
                for (int r = 0; r < 4; r++) {
                    Cb[(size_t)(m0 + wr + i * 16 + cr + r) * KDIMc + coloff +
                       wc + j * 16 + fr] = f2bf(acc[i][j][r]);
                }
            }
    } else {
        const int coloff = (bx - 16) << 7;
#pragma unroll
        for (int i = 0; i < 4; i++)
#pragma unroll
            for (int j = 0; j < 4; j++) {
#pragma unroll
                for (int r = 0; r < 4; r++) {
                    vb[(size_t)(m0 + wr + i * 16 + cr + r) * VDIMc + coloff +
                       wc + j * 16 + fr] = acc[i][j][r];
                }
            }
    }
}

// ---------------------------------------------------------------------------
// bf16 MFMA GEMM (generic): C f32 = A @ Bt. For output projection.
// ---------------------------------------------------------------------------
__global__ void __launch_bounds__(256) gemm_bf16(
    const unsigned short* __restrict__ A, const unsigned short* __restrict__ Bt,
    float* __restrict__ C, int M, int N, int K) {
    GEMM_SHARED();
    XCD_SWZ();
    const int tid = threadIdx.x;
    const int nbx = N >> 7;
    const int bx = bid % nbx, by = bid / nbx;
    const int m0 = by << 7, n0 = bx << 7;
    const int w = tid >> 6, lane = tid & 63;
    const int wr = (w >> 1) << 6, wc = (w & 1) << 6;
    const int fr = lane & 15, fk8 = (lane >> 4) << 3;
    const int grow = lane >> 2;
    const int gcol = (lane & 3) << 3;

    f32x4 acc[4][4];
#pragma unroll
    for (int i = 0; i < 4; i++)
#pragma unroll
        for (int j = 0; j < 4; j++)
            acc[i][j] = (f32x4){0.f, 0.f, 0.f, 0.f};

    GEMM_KLOOP(A, Bt, K);

    const int cr = (lane >> 4) << 2;
#pragma unroll
    for (int i = 0; i < 4; i++)
#pragma unroll
        for (int j = 0; j < 4; j++) {
#pragma unroll
            for (int r = 0; r < 4; r++) {
                C[(size_t)(m0 + wr + i * 16 + cr + r) * N + n0 + wc + j * 16 +
                  fr] = acc[i][j][r];
            }
        }
}

// ---------------------------------------------------------------------------
// Gate GEMM fused with gated RMSNorm epilogue; o read as bf16.
// ---------------------------------------------------------------------------
__global__ void __launch_bounds__(256) gemm_gate_rms(
    const unsigned short* __restrict__ A, const unsigned short* __restrict__ Bt,
    const unsigned short* __restrict__ o, const float* __restrict__ rfac,
    const float* __restrict__ norm_w, unsigned short* __restrict__ out,
    int M, int N, int K) {
    GEMM_SHARED();
    XCD_SWZ();
    const int tid = threadIdx.x;
    const int nbx = N >> 7;
    const int bx = bid % nbx, by = bid / nbx;
    const int m0 = by << 7, n0 = bx << 7;
    const int h = n0 >> 7;
    const int w = tid >> 6, lane = tid & 63;
    const int wr = (w >> 1) << 6, wc = (w & 1) << 6;
    const int fr = lane & 15, fk8 = (lane >> 4) << 3;
    const int grow = lane >> 2;
    const int gcol = (lane & 3) << 3;

    f32x4 acc[4][4];
#pragma unroll
    for (int i = 0; i < 4; i++)
#pragma unroll
        for (int j = 0; j < 4; j++)
            acc[i][j] = (f32x4){0.f, 0.f, 0.f, 0.f};

    GEMM_KLOOP(A, Bt, K);

    const int cr = (lane >> 4) << 2;
#pragma unroll
    for (int i = 0; i < 4; i++)
#pragma unroll
        for (int j = 0; j < 4; j++) {
            const int colh = wc + j * 16 + fr;
            const float nw = norm_w[colh];
#pragma unroll
            for (int r = 0; r < 4; r++) {
                const int row = m0 + wr + i * 16 + cr + r;
                float ov = bf2f(o[(size_t)row * VDIMc + n0 + colh]);
                float f = rfac[(size_t)row * Hc + h];
                float y = ov * f * nw * siluf(acc[i][j][r]);
                out[(size_t)row * VDIMc + n0 + colh] = f2bf(y);
            }
        }
}

// ---------------------------------------------------------------------------
// Per-(row,h) RMS factor from bf16 o: rf = rsqrt(mean(o^2)+eps).
// ---------------------------------------------------------------------------
__global__ void __launch_bounds__(256) rfac_kernel(
    const unsigned short* __restrict__ o, float* __restrict__ rf) {
    const int row = blockIdx.x * 4 + (threadIdx.x >> 6);
    const int lane = threadIdx.x & 63;
    const size_t base = (size_t)row * DVc;
    unsigned int pv = *(const unsigned int*)&o[base + lane * 2];
    float o0 = bf2f((unsigned short)(pv & 0xffff));
    float o1 = bf2f((unsigned short)(pv >> 16));
    float ss = o0 * o0 + o1 * o1;
#pragma unroll
    for (int m = 1; m < 64; m <<= 1) ss += __shfl_xor(ss, m, 64);
    if (lane == 0) rf[row] = rsqrtf(ss * (1.f / 128.f) + 1e-5f);
}

// ---------------------------------------------------------------------------
// a/b projections: transposed f32 weights, one wave per 4 rows.
// ---------------------------------------------------------------------------
__global__ void __launch_bounds__(256) ab_proj(
    const float* __restrict__ x, const float* __restrict__ w_aT,
    const float* __restrict__ w_bT, const float* __restrict__ A_log,
    const float* __restrict__ dt_bias, float* __restrict__ g_out,
    float* __restrict__ beta_out) {
    const int wv = threadIdx.x >> 6;
    const int lane = threadIdx.x & 63;
    const int h = lane >> 2, kg = lane & 3;
    const int row0 = blockIdx.x * 16 + wv * 4;
    const float* wa = w_aT + (size_t)h * Dc + kg * 256;
    const float* wb = w_bT + (size_t)h * Dc + kg * 256;
    const float* xr = x + (size_t)row0 * Dc + kg * 256;
    float pa[4] = {0.f, 0.f, 0.f, 0.f}, pb[4] = {0.f, 0.f, 0.f, 0.f};
#pragma unroll 4
    for (int k = 0; k < 256; k += 4) {
        float4 a4 = *(const float4*)&wa[k];
        float4 b4 = *(const float4*)&wb[k];
#pragma unroll
        for (int r = 0; r < 4; r++) {
            float4 x4 = *(const float4*)&xr[(size_t)r * Dc + k];
            pa[r] += dot4(x4, a4);
            pb[r] += dot4(x4, b4);
        }
    }
#pragma unroll
    for (int r = 0; r < 4; r++) {
        pa[r] += __shfl_xor(pa[r], 1, 64);
        pa[r] += __shfl_xor(pa[r], 2, 64);
        pb[r] += __shfl_xor(pb[r], 1, 64);
        pb[r] += __shfl_xor(pb[r], 2, 64);
    }
    if (kg == 0) {
        const float el = __expf(A_log[h]);
        const float db = dt_bias[h];
#pragma unroll
        for (int r = 0; r < 4; r++) {
            float arg = pa[r] + db;
            float sp = fmaxf(arg, 0.f) + log1pf(__expf(-fabsf(arg)));
            g_out[(size_t)(row0 + r) * Hc + h] = -el * sp;
            beta_out[(size_t)(row0 + r) * Hc + h] =
                2.f / (1.f + __expf(-pb[r]));
        }
    }
}

// ---------------------------------------------------------------------------
// Save 3-row halos at 64-step chunk boundaries (for in-place v conv).
// ---------------------------------------------------------------------------
template <int C>
__global__ void __launch_bounds__(256) save_halo(
    const float* __restrict__ in, float* __restrict__ halo) {
    const int g = blockIdx.x * 256 + threadIdx.x;
    const int total = Bc * (Tc / 64 - 1) * 3 * C;
    if (g >= total) return;
    const int c = g % C;
    int r = g / C;
    const int j = r % 3;
    r /= 3;
    const int chunk = r % (Tc / 64 - 1) + 1;
    const int b = r / (Tc / 64 - 1);
    halo[((size_t)(b * 64 + chunk) * 3 + j) * C + c] =
        in[((size_t)b * Tc + chunk * 64 - 3 + j) * C + c];
}

// ---------------------------------------------------------------------------
// Fused q+k depthwise causal conv1d + SiLU + l2norm, bf16->bf16.
// ---------------------------------------------------------------------------
__global__ void __launch_bounds__(256) conv_qk(
    const unsigned short* __restrict__ qin, const float* __restrict__ wq,
    unsigned short* __restrict__ qout, const unsigned short* __restrict__ kin,
    const float* __restrict__ wk, unsigned short* __restrict__ kout) {
    constexpr int C = KDIMc;
    constexpr int CB = C / 256;
    const int half = Bc * (Tc / 64) * CB;
    int bidx = blockIdx.x;
    const unsigned short* in;
    const float* w;
    unsigned short* out;
    if (bidx < half) { in = qin; w = wq; out = qout; }
    else { bidx -= half; in = kin; w = wk; out = kout; }
    const int cb = bidx % CB;
    const int tchunk = (bidx / CB) % (Tc / 64);
    const int b = bidx / (CB * (Tc / 64));
    const int c = cb * 256 + threadIdx.x;
    const int t0 = tchunk * 64;
    const float w0 = w[c * 4 + 0], w1 = w[c * 4 + 1], w2 = w[c * 4 + 2],
                w3 = w[c * 4 + 3];
    const unsigned short* src = in + (size_t)b * Tc * C + c;
    float xm3 = (t0 >= 3) ? bf2f(src[(size_t)(t0 - 3) * C]) : 0.f;
    float xm2 = (t0 >= 2) ? bf2f(src[(size_t)(t0 - 2) * C]) : 0.f;
    float xm1 = (t0 >= 1) ? bf2f(src[(size_t)(t0 - 1) * C]) : 0.f;
    unsigned short* dst = out + (size_t)b * Tc * C + c;
#pragma unroll 4
    for (int i = 0; i < 64; i++) {
        float xt = bf2f(src[(size_t)(t0 + i) * C]);
        float y = w0 * xm3 + w1 * xm2 + w2 * xm1 + w3 * xt;
        y = siluf(y);
        {
            float ss = y * y;
#pragma unroll
            for (int m = 1; m < 64; m <<= 1) ss += __shfl_xor(ss, m, 64);
            y *= rsqrtf(ss + 1e-6f);
        }
        dst[(size_t)(t0 + i) * C] = f2bf(y);
        xm3 = xm2;
        xm2 = xm1;
        xm1 = xt;
    }
}

// ---------------------------------------------------------------------------
// Depthwise causal conv1d (K=4) + SiLU, IN PLACE f32 (for v).
// ---------------------------------------------------------------------------
template <int C, bool L2N>
__global__ void __launch_bounds__(256) conv_silu_inplace(
    float* __restrict__ buf, const float* __restrict__ w,
    const float* __restrict__ halo) {
    constexpr int CB = C / 256;
    const int bidx = blockIdx.x;
    const int cb = bidx % CB;
    const int tchunk = (bidx / CB) % (Tc / 64);
    const int b = bidx / (CB * (Tc / 64));
    const int c = cb * 256 + threadIdx.x;
    const int t0 = tchunk * 64;
    const float w0 = w[c * 4 + 0], w1 = w[c * 4 + 1], w2 = w[c * 4 + 2],
                w3 = w[c * 4 + 3];
    float xm3 = 0.f, xm2 = 0.f, xm1 = 0.f;
    if (tchunk > 0) {
        const float* hp = halo + (size_t)(b * 64 + tchunk) * 3 * C + c;
        xm3 = hp[0];
        xm2 = hp[C];
        xm1 = hp[2 * C];
    }
    float* p = buf + (size_t)b * Tc * C + c;
#pragma unroll 4
    for (int i = 0; i < 64; i++) {
        float xt = p[(size_t)(t0 + i) * C];
        float y = w0 * xm3 + w1 * xm2 + w2 * xm1 + w3 * xt;
        y = siluf(y);
        if (L2N) {
            float ss = y * y;
#pragma unroll
            for (int m = 1; m < 64; m <<= 1) ss += __shfl_xor(ss, m, 64);
            y *= rsqrtf(ss + 1e-6f);
        }
        p[(size_t)(t0 + i) * C] = y;
        xm3 = xm2;
        xm2 = xm1;
        xm1 = xt;
    }
}

// ---------------------------------------------------------------------------
// TM precompute: Gram via bf16 MFMA, f32 solve (readlane broadcast).
// T,M stored bf16 [t][s].
// ---------------------------------------------------------------------------
__global__ void __launch_bounds__(256) tm_precompute(
    const unsigned short* __restrict__ kc, const unsigned short* __restrict__ qc,
    const float* __restrict__ g, const float* __restrict__ beta,
    unsigned short* __restrict__ tmT, unsigned short* __restrict__ tmM) {
    const int bid = blockIdx.x;
    const int ch = bid & (NCH - 1);
    const int bh = bid >> 6;
    const int b = bh >> 4, h = bh & 15;
    const int tid = threadIdx.x;
    const int t0 = ch * CC;

    __shared__ __align__(16) unsigned short kb16[CC][72];
    __shared__ __align__(16) unsigned short qb16[CC][72];
    __shared__ __align__(16) float AtL[CC][DKc + 4];  // A^T: AtL[s][t]
    __shared__ float cL[CC], betaL[CC];

    const size_t qk0 = (size_t)b * Tc * KDIMc + h * DKc;
    const size_t gb0 = (size_t)b * Tc * Hc + h;
    const size_t tile = (size_t)(bh * NCH + ch) * 4096;

#pragma unroll
    for (int i = 0; i < 2; i++) {
        int e = tid + i * 256;
        int r = e >> 3, c8 = (e & 7) << 3;
        *(short8*)&kb16[r][c8] =
            *(const short8*)&kc[qk0 + (size_t)(t0 + r) * KDIMc + c8];
        *(short8*)&qb16[r][c8] =
            *(const short8*)&qc[qk0 + (size_t)(t0 + r) * KDIMc + c8];
    }
    if (tid < 64) {
        float gv = g[gb0 + (size_t)(t0 + tid) * Hc];
        float cv = gv;
#pragma unroll
        for (int d = 1; d < 64; d <<= 1) {
            float nb = __shfl_up(cv, d, 64);
            if (tid >= d) cv += nb;
        }
        cL[tid] = cv;
        betaL[tid] = beta[gb0 + (size_t)(t0 + tid) * Hc];
    }
    __syncthreads();

    {
        const int w = tid >> 6, lane = tid & 63;
        const int fr = lane & 15, fk8 = (lane >> 4) << 3;
        const int rr = (lane >> 4) << 2;
        short8 ak0 = *(const short8*)&kb16[w * 16 + fr][fk8];
        short8 ak1 = *(const short8*)&kb16[w * 16 + fr][fk8 + 32];
        short8 aq0 = *(const short8*)&qb16[w * 16 + fr][fk8];
        short8 aq1 = *(const short8*)&qb16[w * 16 + fr][fk8 + 32];
#pragma unroll
        for (int j = 0; j < 4; j++) {
            short8 b0 = *(const short8*)&kb16[j * 16 + fr][fk8];
            short8 b1 = *(const short8*)&kb16[j * 16 + fr][fk8 + 32];
            f32x4 kk = (f32x4){0.f, 0.f, 0.f, 0.f};
            f32x4 qk = (f32x4){0.f, 0.f, 0.f, 0.f};
            kk = __builtin_amdgcn_mfma_f32_16x16x32_bf16(ak0, b0, kk, 0, 0, 0);
            kk = __builtin_amdgcn_mfma_f32_16x16x32_bf16(ak1, b1, kk, 0, 0, 0);
            qk = __builtin_amdgcn_mfma_f32_16x16x32_bf16(aq0, b0, qk, 0, 0, 0);
            qk = __builtin_amdgcn_mfma_f32_16x16x32_bf16(aq1, b1, qk, 0, 0, 0);
#pragma unroll
            for (int r = 0; r < 4; r++) {
                int t = w * 16 + rr + r, s = j * 16 + fr;
                float E = (s <= t) ? __expf(cL[t] - cL[s]) : 0.f;
                AtL[s][t] = (s < t) ? betaL[t] * E * kk[r] : 0.f;
                tmM[tile + (size_t)t * 64 + s] =
                    (s <= t) ? f2bf(0.125f * E * qk[r]) : (unsigned short)0;
            }
        }
    }
    __syncthreads();

    {
        const int w = tid >> 6, lane = tid & 63;
        float acc[16];
#pragma unroll
        for (int di = 0; di < 16; di++)
            acc[di] = (lane == w * 16 + di) ? 1.f : 0.f;
        // Forward substitution, fully unrolled; readlane broadcast (SALU).
#pragma unroll
        for (int s = 0; s < 64; s++) {
            float a = AtL[s][lane];
            float ds[16];
#pragma unroll
            for (int di = 0; di < 16; di++)
                ds[di] = __uint_as_float(
                    __builtin_amdgcn_readlane(__float_as_uint(acc[di]), s));
#pragma unroll
            for (int di = 0; di < 16; di++)
                acc[di] = fmaf(-a, ds[di], acc[di]);
        }
        unsigned short tb[16];
#pragma unroll
        for (int di = 0; di < 16; di++) tb[di] = f2bf(acc[di]);
        *(uint4*)&tmT[tile + (size_t)lane * 64 + w * 16] = *(uint4*)&tb[0];
        *(uint4*)&tmT[tile + (size_t)lane * 64 + w * 16 + 8] = *(uint4*)&tb[8];
    }
}

// ---------------------------------------------------------------------------
// Sequential chunk scan (R19-proven): conflict-free K^T staging, all-MFMA
// phases, register-resident S, V read f32, O stored bf16. 8-way DV split.
// ---------------------------------------------------------------------------
__global__ void __launch_bounds__(512, 2) delta_scan(
    const unsigned short* __restrict__ kc, const unsigned short* __restrict__ qc,
    const unsigned short* __restrict__ kcT,  // [B][KDIM][T]
    const float* __restrict__ vc, unsigned short* __restrict__ o16,
    const float* __restrict__ g, const float* __restrict__ beta,
    const unsigned short* __restrict__ tmT,
    const unsigned short* __restrict__ tmM) {
    const int bid = blockIdx.x;
    const int sl = bid >> 5;   // 0..7
    const int bh = bid & 31;   // 0..31 -> XCD = bh%8
    const int b = bh >> 4, h = bh & 15;
    const int tid = threadIdx.x;

    __shared__ __align__(16) float VL[CC][20];
    __shared__ float gamL[CC], egL[CC], betaL[CC];
    __shared__ __align__(16) unsigned short kb16[CC][72];  // K rows
    __shared__ __align__(16) unsigned short kh16[CC][72];  // K^T: [dk][t]
    __shared__ __align__(16) unsigned short qb16[CC][72];
    __shared__ __align__(16) unsigned short Tb16[CC][72];
    __shared__ __align__(16) unsigned short Mb16[CC][72];
    __shared__ __align__(16) unsigned short STb16[16][72];  // S^T bf16 copy
    __shared__ __align__(16) unsigned short DTb16[16][72];  // RHS^T bf16
    __shared__ __align__(16) unsigned short D2b16[16][72];  // delta^T bf16
    __shared__ __align__(16) unsigned short egd16[16][72];  // (eg*delta)^T

    const size_t qk0 = (size_t)b * Tc * KDIMc + h * DKc;
    const size_t kT0 = ((size_t)b * KDIMc + h * DKc) * Tc;
    const size_t v0 = (size_t)b * Tc * VDIMc + h * DVc + sl * 16;
    const size_t gb0 = (size_t)b * Tc * Hc + h;
    const size_t tb0 = (size_t)(bh * NCH) * 4096;

    for (int i = tid; i < 16 * 72; i += 512) ((unsigned short*)STb16)[i] = 0;

    const int r8 = tid >> 3, c8 = (tid & 7) << 3;  // bf16 staging coords
    const int wid = tid >> 6, lane = tid & 63;
    const int fr = lane & 15;
    const int fk8 = (lane >> 4) << 3;
    const int rr = (lane >> 4) << 2;

    f32x4 accS = (f32x4){0.f, 0.f, 0.f, 0.f};  // waves 0-3: S[w*16+rr+r][fr]

    short8 kv, kvT, qv, tv, mv;
    float4 vv0;
    float gvr = 0.f, bvr = 0.f;

#define LOADREGS(CH)                                                          \
    {                                                                         \
        const size_t tK = qk0 + (size_t)(CH) * CC * KDIMc;                    \
        const size_t tile_ = tb0 + (size_t)(CH) * 4096;                       \
        kv = *(const short8*)&kc[tK + (size_t)r8 * KDIMc + c8];               \
        kvT = *(const short8*)&kcT[kT0 + (size_t)r8 * Tc + (CH) * CC + c8];   \
        qv = *(const short8*)&qc[tK + (size_t)r8 * KDIMc + c8];               \
        tv = *(const short8*)&tmT[tile_ + (size_t)tid * 8];                   \
        mv = *(const short8*)&tmM[tile_ + (size_t)tid * 8];                   \
        if (tid < 256)                                                        \
            vv0 = *(const float4*)&vc[v0 +                                    \
                                      (size_t)((CH) * CC + (tid >> 2)) *     \
                                          VDIMc +                             \
                                      ((tid & 3) << 2)];                      \
        if (tid < 64) {                                                       \
            gvr = g[gb0 + (size_t)((CH) * CC + tid) * Hc];                    \
            bvr = beta[gb0 + (size_t)((CH) * CC + tid) * Hc];                 \
        }                                                                     \
    }

    LOADREGS(0);

#pragma unroll 1
    for (int ch = 0; ch < NCH; ch++) {
        __syncthreads();  // B0: prev chunk fully done (STb16 visible)

        // ---- stage regs -> LDS (pure short8 copies; no conversions)
        {
            *(short8*)&kb16[r8][c8] = kv;
            *(short8*)&kh16[r8][c8] = kvT;
            *(short8*)&qb16[r8][c8] = qv;
            *(short8*)&Tb16[r8][c8] = tv;
            *(short8*)&Mb16[r8][c8] = mv;
            if (tid < 256) *(float4*)&VL[tid >> 2][(tid & 3) << 2] = vv0;
            if (tid < 64) {
                float cv = gvr;
#pragma unroll
                for (int d = 1; d < 64; d <<= 1) {
                    float nb = __shfl_up(cv, d, 64);
                    if (tid >= d) cv += nb;
                }
                gamL[tid] = __expf(cv);
                float cend = __shfl(cv, 63, 64);
                egL[tid] = __expf(cend - cv);
                betaL[tid] = bvr;
            }
        }
        if (ch + 1 < NCH) LOADREGS(ch + 1);
        __syncthreads();  // B1: stage visible

        // ---- phase 1: KS (waves 0-3) and QS (waves 4-7) via MFMA
        f32x4 acc1 = (f32x4){0.f, 0.f, 0.f, 0.f};
        {
            short8 bs0 = *(const short8*)&STb16[fr][fk8];
            short8 bs1 = *(const short8*)&STb16[fr][fk8 + 32];
            if (wid < 4) {
                const int m0 = wid << 4;
                short8 a0 = *(const short8*)&kb16[m0 + fr][fk8];
                short8 a1 = *(const short8*)&kb16[m0 + fr][fk8 + 32];
                acc1 = __builtin_amdgcn_mfma_f32_16x16x32_bf16(a0, bs0, acc1, 0, 0, 0);
                acc1 = __builtin_amdgcn_mfma_f32_16x16x32_bf16(a1, bs1, acc1, 0, 0, 0);
#pragma unroll
                for (int r = 0; r < 4; r++) {
                    int t = m0 + rr + r;
                    float rhs = betaL[t] * (VL[t][fr] - gamL[t] * acc1[r]);
                    DTb16[fr][t] = f2bf(rhs);
                }
            } else {
                const int m0 = (wid - 4) << 4;
                short8 a0 = *(const short8*)&qb16[m0 + fr][fk8];
                short8 a1 = *(const short8*)&qb16[m0 + fr][fk8 + 32];
                acc1 = __builtin_amdgcn_mfma_f32_16x16x32_bf16(a0, bs0, acc1, 0, 0, 0);
                acc1 = __builtin_amdgcn_mfma_f32_16x16x32_bf16(a1, bs1, acc1, 0, 0, 0);
#pragma unroll
                for (int r = 0; r < 4; r++) {
                    int t = m0 + rr + r;
                    acc1[r] *= 0.125f * gamL[t];
                }
            }
        }
        __syncthreads();  // B2: RHS ready

        // ---- phase 2: delta = T * RHS (waves 0-3); write delta and eg*delta
        if (wid < 4) {
            const int m0 = wid << 4;
            short8 a0 = *(const short8*)&Tb16[m0 + fr][fk8];
            short8 a1 = *(const short8*)&Tb16[m0 + fr][fk8 + 32];
            short8 b0 = *(const short8*)&DTb16[fr][fk8];
            short8 b1 = *(const short8*)&DTb16[fr][fk8 + 32];
            f32x4 d = (f32x4){0.f, 0.f, 0.f, 0.f};
            d = __builtin_amdgcn_mfma_f32_16x16x32_bf16(a0, b0, d, 0, 0, 0);
            d = __builtin_amdgcn_mfma_f32_16x16x32_bf16(a1, b1, d, 0, 0, 0);
#pragma unroll
            for (int r = 0; r < 4; r++) {
                int t = m0 + rr + r;
                D2b16[fr][t] = f2bf(d[r]);
                egd16[fr][t] = f2bf(egL[t] * d[r]);
            }
        }
        __syncthreads();  // B3: delta ready

        // ---- phase 3 (waves 4-7): O = M*delta + scaledQS, store bf16.
        //      phase 4 (waves 0-3): S = ge*S + K^T(eg*delta) via MFMA.
        if (wid >= 4) {
            const int m0 = (wid - 4) << 4;
            short8 a0 = *(const short8*)&Mb16[m0 + fr][fk8];
            short8 a1 = *(const short8*)&Mb16[m0 + fr][fk8 + 32];
            short8 b0 = *(const short8*)&D2b16[fr][fk8];
            short8 b1 = *(const short8*)&D2b16[fr][fk8 + 32];
            f32x4 o = acc1;  // 0.125*gam*QS
            o = __builtin_amdgcn_mfma_f32_16x16x32_bf16(a0, b0, o, 0, 0, 0);
            o = __builtin_amdgcn_mfma_f32_16x16x32_bf16(a1, b1, o, 0, 0, 0);
#pragma unroll
            for (int r = 0; r < 4; r++)
                o16[v0 + (size_t)(ch * CC + m0 + rr + r) * VDIMc + fr] =
                    f2bf(o[r]);
        } else {
            const int m0 = wid << 4;
            const float ge = gamL[63];
            short8 a0 = *(const short8*)&kh16[m0 + fr][fk8];
            short8 a1 = *(const short8*)&kh16[m0 + fr][fk8 + 32];
            short8 b0 = *(const short8*)&egd16[fr][fk8];
            short8 b1 = *(const short8*)&egd16[fr][fk8 + 32];
#pragma unroll
            for (int r = 0; r < 4; r++) accS[r] *= ge;
            accS = __builtin_amdgcn_mfma_f32_16x16x32_bf16(a0, b0, accS, 0, 0, 0);
            accS = __builtin_amdgcn_mfma_f32_16x16x32_bf16(a1, b1, accS, 0, 0, 0);
#pragma unroll
            for (int r = 0; r < 4; r++)
                STb16[fr][m0 + rr + r] = f2bf(accS[r]);
        }
    }
#undef LOADREGS
}

// ---------------------------------------------------------------------------
// Workspace (floats), 236 MB (R18/R19-proven layout):
//   qb 8.39M (q16raw -> kcT16) | kb 8.39M (k16raw -> o16) | vb 16.78M f32 |
//   tm-region 16.78M (tmT16|tmM16|qc16|kc16 shorts; halo aliases start) |
//   gbuf | bbuf | xtra.  obb aliases tm start (after scan); rfac = gbuf.
// ---------------------------------------------------------------------------
extern "C" void kernel_launch(void* const* d_in, const int* in_sizes, int n_in,
                              void* d_out, int out_size, void* d_ws,
                              size_t ws_size, hipStream_t stream) {
    const float* x = (const float*)d_in[0];
    const float* w_q = (const float*)d_in[1];
    const float* w_k = (const float*)d_in[2];
    const float* w_v = (const float*)d_in[3];
    const float* w_a = (const float*)d_in[4];
    const float* w_b = (const float*)d_in[5];
    const float* w_g = (const float*)d_in[6];
    const float* w_out = (const float*)d_in[7];
    const float* A_log = (const float*)d_in[8];
    const float* dt_bias = (const float*)d_in[9];
    const float* conv_q = (const float*)d_in[10];
    const float* conv_k = (const float*)d_in[11];
    const float* conv_v = (const float*)d_in[12];
    const float* norm_w = (const float*)d_in[13];

    float* ws = (float*)d_ws;
    const size_t M = Mrows;
    float* qb = ws;
    float* kb = qb + M * KDIMc;
    float* vb = kb + M * KDIMc;
    float* tm = vb + M * VDIMc;          // 16.78M floats region
    float* gbuf = tm + M * VDIMc;
    float* bbuf = gbuf + M * Hc;
    float* xtra = bbuf + M * Hc;

    unsigned short* q16raw = (unsigned short*)qb;
    unsigned short* k16raw = (unsigned short*)kb;
    unsigned short* kcT16 = (unsigned short*)qb;  // alias: after conv_q
    unsigned short* o16 = (unsigned short*)kb;    // alias: after conv_k
    unsigned short* tmS = (unsigned short*)tm;
    unsigned short* tmT16 = tmS;
    unsigned short* tmM16 = tmS + (size_t)8388608;
    unsigned short* qc16 = tmS + (size_t)16777216;
    unsigned short* kc16 = tmS + (size_t)25165824;
    float* halo = tm;                     // dead before tm_precompute
    unsigned short* obb = tmS;            // after scan, tmT/tmM dead
    float* rfac = gbuf;                   // g dead after scan

    unsigned short* xb = (unsigned short*)xtra;
    unsigned short* wqT = xb + M * KDIMc;
    unsigned short* wkT = wqT + (size_t)KDIMc * Dc;
    unsigned short* wvT = wkT + (size_t)KDIMc * Dc;  // wqT|wkT|wvT contiguous
    unsigned short* wgT = wvT + (size_t)VDIMc * Dc;
    unsigned short* woT = wgT + (size_t)VDIMc * Dc;
    float* waT = (float*)(woT + (size_t)Dc * VDIMc);
    float* wbT = waT + (size_t)16 * Dc;

    // 0) fused prep: weight transposes + a/b transposes + x convert
    prep_all<<<dim3(1024 + 1024 + 2048 + 2048 + 2048 + 16 + 16 + 8192), 256,
               0, stream>>>(x, w_q, w_k, w_v, w_g, w_out, w_a, w_b, xb, wqT,
                            wkT, wvT, wgT, woT, waT, wbT);

    // 1) fused q/k/v projection (counted-vmcnt pipeline + XCD swizzle)
    gemm_qkv<<<dim3((M / 128) * 32), 256, 0, stream>>>(xb, wqT, q16raw, k16raw,
                                                       vb);

    // 2) a/b projections -> g, beta
    ab_proj<<<dim3(M / 16), 256, 0, stream>>>(x, waT, wbT, A_log, dt_bias,
                                              gbuf, bbuf);

    // 3) conv + silu: fused q+k bf16->bf16 (+l2norm); v in-place f32
    conv_qk<<<dim3(2 * Bc * (Tc / 64) * (KDIMc / 256)), 256, 0, stream>>>(
        q16raw, conv_q, qc16, k16raw, conv_k, kc16);
    // kcT16 = kc16 transposed to [B][KDIM][T] (aliases qb; conv_q done)
    transp_k16<<<dim3(Bc * 16 * 64), 256, 0, stream>>>(kc16, kcT16);
    {
        const int nv = Bc * (Tc / 64 - 1) * 3 * VDIMc;
        save_halo<VDIMc><<<dim3((nv + 255) / 256), 256, 0, stream>>>(vb, halo);
        conv_silu_inplace<VDIMc, false>
            <<<dim3(Bc * (Tc / 64) * (VDIMc / 256)), 256, 0, stream>>>(
                vb, conv_v, halo);
    }

    // 4a) parallel precompute of T=(I+A)^{-1} and M (bf16 out)
    tm_precompute<<<dim3(Bc * Hc * NCH), 256, 0, stream>>>(
        kc16, qc16, gbuf, bbuf, tmT16, tmM16);
    // 4b) sequential scan (8-way DV split, R19-proven)
    delta_scan<<<dim3(Bc * Hc * 8), 512, 0, stream>>>(
        kc16, qc16, kcT16, vb, o16, gbuf, bbuf, tmT16, tmM16);

    // 5) rms factors from bf16 o, then gate GEMM fused with rms epilogue
    rfac_kernel<<<dim3(M * Hc / 4), 256, 0, stream>>>(o16, rfac);
    gemm_gate_rms<<<dim3((M / 128) * (VDIMc / 128)), 256, 0, stream>>>(
        xb, wgT, o16, rfac, norm_w, obb, M, VDIMc, Dc);

    // 6) output projection (counted-vmcnt pipeline + XCD swizzle) -> d_out
    gemm_bf16<<<dim3((M / 128) * (Dc / 128)), 256, 0, stream>>>(
        obb, woT, (float*)d_out, M, Dc, VDIMc);
}